// Round 2
// baseline (3996.059 us; speedup 1.0000x reference)
//
#include <hip/hip_runtime.h>
#include <hip/hip_bf16.h>

// ---------- helpers ----------
__device__ __forceinline__ float bf2f(unsigned short u) {
    union { unsigned int i; float f; } x;
    x.i = ((unsigned int)u) << 16;
    return x.f;
}
__device__ __forceinline__ unsigned short f2bf(float f) {
    union { float f; unsigned int u; } x; x.f = f;
    unsigned int r = x.u + 0x7FFFu + ((x.u >> 16) & 1u);
    return (unsigned short)(r >> 16);
}

// ---------- workspace byte offsets (total ~192.93 MB) ----------
#define Z_OFF      0UL            // N*3*256 f32 = 153,600,000
#define XW_OFF     153600000UL    // N*256 bf16  =  25,600,000
#define EI_OFF     179200000UL    // 3*2E int32  =   9,600,000
#define AS_OFF     188800000UL    // N*4 f32
#define AD_OFF     189600000UL
#define M_OFF      190400000UL
#define S_OFF      191200000UL
#define WF_OFF     192000000UL    // 3*256*256 f32 = 786,432
#define ASF_OFF    192786432UL    // 768 f32
#define ADF_OFF    192789504UL
#define BIASF_OFF  192792576UL
#define W1F_OFF    192795648UL    // 32768 f32
#define B1F_OFF    192926720UL    // 128 f32
#define W2F_OFF    192927232UL
#define WSUM_OFF   192927744UL
#define BETA_OFF   192927808UL
#define FLAG_OFF   192927872UL

// ---------- P0: dtype probe (runs every call; inputs identical each call) ----------
__global__ void probe(const unsigned short* __restrict__ hraw,
                      const unsigned int* __restrict__ eraw,
                      int* __restrict__ flags) {
    if (threadIdx.x == 0 && blockIdx.x == 0) {
        // float mode: bf16 halfwords all have sane exponent fields; fp32 low halves don't
        int sane = 0;
        for (int i = 0; i < 256; ++i) {
            unsigned int e = (hraw[i] >> 7) & 0xFF;
            if (hraw[i] != 0 && e >= 100 && e <= 150) sane++;
        }
        flags[0] = (sane >= 220) ? 1 : 0;   // 1 = bf16 inputs/outputs
        // index mode: int64 little-endian -> odd int32 words are all zero
        int zeros = 0;
        for (int i = 1; i < 256; i += 2) if (eraw[i] == 0u) zeros++;
        flags[1] = (zeros >= 120) ? 1 : 0;  // 1 = int64 indices
    }
}

__device__ __forceinline__ float rd_f(const void* p, int j, bool bf) {
    return bf ? bf2f(((const unsigned short*)p)[j]) : ((const float*)p)[j];
}

// ---------- P1: canonicalize params to fp32 ----------
__global__ void ingest_params(const void* W, const void* as, const void* ad, const void* bias,
                              const void* w1, const void* b1, const void* w2,
                              float* Wf, float* asf, float* adf, float* biasf,
                              float* w1f, float* b1f, float* w2f,
                              const int* __restrict__ flags) {
    int i = blockIdx.x * 256 + threadIdx.x;
    bool bf = flags[0] != 0;
    if      (i < 196608)                  Wf[i]              = rd_f(W,   i,          bf);
    else if (i < 196608 + 768)            asf[i - 196608]    = rd_f(as,  i - 196608, bf);
    else if (i < 196608 + 1536)           adf[i - 197376]    = rd_f(ad,  i - 197376, bf);
    else if (i < 196608 + 2304)           biasf[i - 198144]  = rd_f(bias,i - 198144, bf);
    else if (i < 196608 + 2304 + 32768)   w1f[i - 198912]    = rd_f(w1,  i - 198912, bf);
    else if (i < 196608 + 2304 + 32896)   b1f[i - 231680]    = rd_f(b1,  i - 231680, bf);
    else if (i < 196608 + 2304 + 33024)   w2f[i - 231808]    = rd_f(w2,  i - 231808, bf);
}

// ---------- P2: canonicalize indices to int32 ----------
__global__ void ingest_idx(const void* e0, const void* e1, const void* e2,
                           int* __restrict__ dst, int twoE, const int* __restrict__ flags) {
    int i = blockIdx.x * 256 + threadIdx.x;
    if (i >= 3 * twoE) return;
    int p = i / twoE, j = i - p * twoE;
    const void* src = (p == 0) ? e0 : (p == 1) ? e1 : e2;
    int v = flags[1] ? (int)((const long long*)src)[j] : ((const int*)src)[j];
    dst[i] = v;
}

// ---------- K1: xw = h @ W[p]  (fp32 VALU, dtype-adaptive h reads) ----------
__global__ void gemm_xw(const void* __restrict__ h, const float* __restrict__ Wfp,
                        unsigned short* __restrict__ xw, const int* __restrict__ flags) {
    __shared__ float hs[16][257];
    int t = threadIdx.x;               // column 0..255
    int row0 = blockIdx.x * 16;
    bool bf = flags[0] != 0;
#pragma unroll
    for (int it = 0; it < 16; ++it) {
        size_t g = (size_t)(row0 + it) * 256 + t;
        hs[it][t] = bf ? bf2f(((const unsigned short*)h)[g]) : ((const float*)h)[g];
    }
    __syncthreads();
    float acc[16];
#pragma unroll
    for (int r = 0; r < 16; ++r) acc[r] = 0.f;
    for (int k = 0; k < 256; ++k) {
        float wv = Wfp[k * 256 + t];
#pragma unroll
        for (int r = 0; r < 16; ++r) acc[r] += hs[r][k] * wv;
    }
#pragma unroll
    for (int r = 0; r < 16; ++r)
        xw[(size_t)(row0 + r) * 256 + t] = f2bf(acc[r]);
}

// ---------- K2: per-(n,h) attention logits + init m,s ----------
__global__ void alpha_kernel(const unsigned short* __restrict__ xw,
                             const float* __restrict__ att_src,   // [4,64] fp32
                             const float* __restrict__ att_dst,
                             float* __restrict__ as_, float* __restrict__ ad_,
                             unsigned int* __restrict__ mbuf, float* __restrict__ sbuf) {
    int n    = blockIdx.x;
    int wid  = threadIdx.x >> 6;   // head
    int lane = threadIdx.x & 63;   // f
    float x  = bf2f(xw[(size_t)n * 256 + wid * 64 + lane]);
    float vs = x * att_src[wid * 64 + lane];
    float vd = x * att_dst[wid * 64 + lane];
#pragma unroll
    for (int o = 32; o; o >>= 1) {
        vs += __shfl_down(vs, o);
        vd += __shfl_down(vd, o);
    }
    if (lane == 0) {
        int g = n * 4 + wid;
        as_[g] = vs;
        ad_[g] = vd;
        mbuf[g] = 0u;
        sbuf[g] = 0.f;
    }
}

__device__ __forceinline__ void edge_src_dst(const int* ei, int E, int e, int& src, int& dst) {
    if (e < E) { src = ei[e]; dst = ei[E + e]; }
    else       { src = dst = e - E; }
}
__device__ __forceinline__ float leaky(float v) { return v > 0.f ? v : 0.2f * v; }
__device__ __forceinline__ unsigned int fmap(float v) {
    unsigned int u = __float_as_uint(v);
    return (u & 0x80000000u) ? ~u : (u | 0x80000000u);
}
__device__ __forceinline__ float funmap(unsigned int u) {
    unsigned int b = (u & 0x80000000u) ? (u & 0x7fffffffu) : ~u;
    return __uint_as_float(b);
}

// ---------- K3: segment max ----------
__global__ void edge_max(const int* __restrict__ ei, int E, int N,
                         const float* __restrict__ as_, const float* __restrict__ ad_,
                         unsigned int* __restrict__ mbuf) {
    int idx = blockIdx.x * blockDim.x + threadIdx.x;
    if (idx >= (E + N) * 4) return;
    int e = idx >> 2, hh = idx & 3;
    int src, dst;
    edge_src_dst(ei, E, e, src, dst);
    float v = leaky(as_[src * 4 + hh] + ad_[dst * 4 + hh]);
    atomicMax(&mbuf[dst * 4 + hh], fmap(v));
}

// ---------- K4: segment sum of exp ----------
__global__ void edge_sum(const int* __restrict__ ei, int E, int N,
                         const float* __restrict__ as_, const float* __restrict__ ad_,
                         const unsigned int* __restrict__ mbuf, float* __restrict__ sbuf) {
    int idx = blockIdx.x * blockDim.x + threadIdx.x;
    if (idx >= (E + N) * 4) return;
    int e = idx >> 2, hh = idx & 3;
    int src, dst;
    edge_src_dst(ei, E, e, src, dst);
    float v  = leaky(as_[src * 4 + hh] + ad_[dst * 4 + hh]);
    float mf = funmap(mbuf[dst * 4 + hh]);
    atomicAdd(&sbuf[dst * 4 + hh], __expf(v - mf));
}

// ---------- K5: weighted aggregation into z[:,p,:] ----------
__global__ void edge_agg(const int* __restrict__ ei, int E, int N, int p,
                         const float* __restrict__ as_, const float* __restrict__ ad_,
                         const unsigned int* __restrict__ mbuf, const float* __restrict__ sbuf,
                         const unsigned short* __restrict__ xw, float* __restrict__ z) {
    int e = blockIdx.x;
    int t = threadIdx.x;           // 0..255 -> (h = t>>6, f = t&63)
    int hh = t >> 6;
    int src, dst;
    edge_src_dst(ei, E, e, src, dst);
    float v     = leaky(as_[src * 4 + hh] + ad_[dst * 4 + hh]);
    float mf    = funmap(mbuf[dst * 4 + hh]);
    float alpha = __expf(v - mf) / sbuf[dst * 4 + hh];
    float x     = bf2f(xw[(size_t)src * 256 + t]);
    atomicAdd(&z[((size_t)dst * 3 + p) * 256 + t], alpha * x);
}

// ---------- K6: semantic attention projection -> wsum[p] ----------
__global__ void sem_w(const float* __restrict__ z,
                      const float* __restrict__ biasf,   // [3,256]
                      const float* __restrict__ w1f,     // [256,128]
                      const float* __restrict__ b1f,     // [128]
                      const float* __restrict__ w2f,     // [128]
                      float* __restrict__ wsum) {
    __shared__ float zs[8][256];
    __shared__ float red[2];
    int j  = threadIdx.x;          // hidden unit 0..127
    int q0 = blockIdx.x * 8;

#pragma unroll
    for (int it = 0; it < 16; ++it) {
        int flat = it * 128 + j;
        int g = flat >> 8, c = flat & 255;
        int q = q0 + g;
        zs[g][c] = z[(size_t)q * 256 + c] + biasf[(q % 3) * 256 + c];
    }
    __syncthreads();

    float acc[8] = {0.f, 0.f, 0.f, 0.f, 0.f, 0.f, 0.f, 0.f};
    for (int c = 0; c < 256; ++c) {
        float w1v = w1f[c * 128 + j];
#pragma unroll
        for (int g = 0; g < 8; ++g) acc[g] += zs[g][c] * w1v;
    }
    float b1j = b1f[j], w2j = w2f[j];
    int lane = j & 63, wid = j >> 6;
    for (int g = 0; g < 8; ++g) {
        float v = tanhf(acc[g] + b1j) * w2j;
#pragma unroll
        for (int o = 32; o; o >>= 1) v += __shfl_down(v, o);
        if (lane == 0) red[wid] = v;
        __syncthreads();
        if (j == 0) atomicAdd(&wsum[(q0 + g) % 3], red[0] + red[1]);
        __syncthreads();
    }
}

// ---------- K7: beta = softmax(mean) ----------
__global__ void beta_kernel(const float* __restrict__ wsum, float* __restrict__ beta, float invN) {
    if (threadIdx.x == 0) {
        float w0 = wsum[0] * invN, w1 = wsum[1] * invN, w2 = wsum[2] * invN;
        float mx = fmaxf(w0, fmaxf(w1, w2));
        float e0 = __expf(w0 - mx), e1 = __expf(w1 - mx), e2 = __expf(w2 - mx);
        float s = e0 + e1 + e2;
        beta[0] = e0 / s; beta[1] = e1 / s; beta[2] = e2 / s;
    }
}

// ---------- K8: out = sum_p beta[p]*(z[:,p,:]+bias[p]), dtype-adaptive store ----------
__global__ void combine(const float* __restrict__ z,
                        const float* __restrict__ biasf,
                        const float* __restrict__ beta,
                        void* __restrict__ out, const int* __restrict__ flags) {
    int idx = blockIdx.x * blockDim.x + threadIdx.x;  // N*256
    int c = idx & 255;
    float b0 = beta[0], b1 = beta[1], b2 = beta[2];
    size_t base = (size_t)(idx >> 8) * 3 * 256 + c;
    float v = b0 * (z[base]       + biasf[c])
            + b1 * (z[base + 256] + biasf[256 + c])
            + b2 * (z[base + 512] + biasf[512 + c]);
    if (flags[0]) ((unsigned short*)out)[idx] = f2bf(v);
    else          ((float*)out)[idx] = v;
}

extern "C" void kernel_launch(void* const* d_in, const int* in_sizes, int n_in,
                              void* d_out, int out_size, void* d_ws, size_t ws_size,
                              hipStream_t stream) {
    const void* h    = d_in[0];
    const void* e0   = d_in[1];
    const void* e1   = d_in[2];
    const void* e2   = d_in[3];
    const void* W    = d_in[4];
    const void* as   = d_in[5];
    const void* ad   = d_in[6];
    const void* bias = d_in[7];
    const void* w1   = d_in[8];
    const void* b1   = d_in[9];
    const void* w2   = d_in[10];

    const int N = in_sizes[0] / 256;   // 50000
    const int E = in_sizes[1] / 2;     // 400000
    const int twoE = 2 * E;

    char* ws = (char*)d_ws;
    float*          z     = (float*)(ws + Z_OFF);
    unsigned short* xw    = (unsigned short*)(ws + XW_OFF);
    int*            eibuf = (int*)(ws + EI_OFF);
    float*          as_   = (float*)(ws + AS_OFF);
    float*          ad_   = (float*)(ws + AD_OFF);
    unsigned int*   mbuf  = (unsigned int*)(ws + M_OFF);
    float*          sbuf  = (float*)(ws + S_OFF);
    float*          Wf    = (float*)(ws + WF_OFF);
    float*          asf   = (float*)(ws + ASF_OFF);
    float*          adf   = (float*)(ws + ADF_OFF);
    float*          biasf = (float*)(ws + BIASF_OFF);
    float*          w1f   = (float*)(ws + W1F_OFF);
    float*          b1f   = (float*)(ws + B1F_OFF);
    float*          w2f   = (float*)(ws + W2F_OFF);
    float*          wsum  = (float*)(ws + WSUM_OFF);
    float*          beta  = (float*)(ws + BETA_OFF);
    int*            flags = (int*)(ws + FLAG_OFF);

    probe<<<1, 64, 0, stream>>>((const unsigned short*)h, (const unsigned int*)e0, flags);
    ingest_params<<<907, 256, 0, stream>>>(W, as, ad, bias, w1, b1, w2,
                                           Wf, asf, adf, biasf, w1f, b1f, w2f, flags);
    ingest_idx<<<(3 * twoE + 255) / 256, 256, 0, stream>>>(e0, e1, e2, eibuf, twoE, flags);

    hipMemsetAsync(z, 0, (size_t)N * 3 * 256 * sizeof(float), stream);
    hipMemsetAsync(wsum, 0, 16, stream);

    int edgeBlocks = ((E + N) * 4 + 255) / 256;
    for (int p = 0; p < 3; ++p) {
        gemm_xw<<<N / 16, 256, 0, stream>>>(h, Wf + p * 65536, xw, flags);
        alpha_kernel<<<N, 256, 0, stream>>>(xw, asf + p * 256, adf + p * 256,
                                            as_, ad_, mbuf, sbuf);
        const int* eip = eibuf + (size_t)p * twoE;
        edge_max<<<edgeBlocks, 256, 0, stream>>>(eip, E, N, as_, ad_, mbuf);
        edge_sum<<<edgeBlocks, 256, 0, stream>>>(eip, E, N, as_, ad_, mbuf, sbuf);
        edge_agg<<<E + N, 256, 0, stream>>>(eip, E, N, p, as_, ad_, mbuf, sbuf, xw, z);
    }

    sem_w<<<(N * 3) / 8, 128, 0, stream>>>(z, biasf, w1f, b1f, w2f, wsum);
    beta_kernel<<<1, 64, 0, stream>>>(wsum, beta, 1.0f / (float)N);
    combine<<<N, 256, 0, stream>>>(z, biasf, beta, d_out, flags);
}

// Round 3
// 1769.994 us; speedup vs baseline: 2.2577x; 2.2577x over previous
//
#include <hip/hip_runtime.h>
#include <hip/hip_bf16.h>

// ---------- helpers ----------
__device__ __forceinline__ float bf2f(unsigned short u) {
    union { unsigned int i; float f; } x;
    x.i = ((unsigned int)u) << 16;
    return x.f;
}
__device__ __forceinline__ unsigned short f2bf(float f) {
    union { float f; unsigned int u; } x; x.f = f;
    unsigned int r = x.u + 0x7FFFu + ((x.u >> 16) & 1u);
    return (unsigned short)(r >> 16);
}

typedef __bf16 bf16x8 __attribute__((ext_vector_type(8)));
typedef float  f32x4  __attribute__((ext_vector_type(4)));

// ---------- workspace byte offsets (total ~192.47 MB) ----------
#define Z_OFF      0UL            // N*3*256 f32 = 153,600,000
#define XW_OFF     153600000UL    // N*256 bf16  =  25,600,000
#define EI_OFF     179200000UL    // 3*2E int32  =   9,600,000
#define AS_OFF     188800000UL    // N*4 f32
#define AD_OFF     189600000UL
#define M_OFF      190400000UL
#define S_OFF      191200000UL
#define WT_OFF     192000000UL    // 3*256*256 bf16 (transposed W) = 393,216
#define W1T_OFF    192393216UL    // 128*256 bf16 (transposed w1)  =  65,536
#define ASF_OFF    192458752UL    // 768 f32
#define ADF_OFF    192461824UL
#define BIASF_OFF  192464896UL
#define B1F_OFF    192467968UL    // 128 f32
#define W2F_OFF    192468480UL
#define WSUM_OFF   192468992UL
#define BETA_OFF   192469056UL
#define FLAG_OFF   192469120UL

// ---------- P0: dtype probe ----------
__global__ void probe(const unsigned short* __restrict__ hraw,
                      const unsigned int* __restrict__ eraw,
                      int* __restrict__ flags) {
    if (threadIdx.x == 0 && blockIdx.x == 0) {
        int sane = 0;
        for (int i = 0; i < 256; ++i) {
            unsigned int e = (hraw[i] >> 7) & 0xFF;
            if (hraw[i] != 0 && e >= 100 && e <= 150) sane++;
        }
        flags[0] = (sane >= 220) ? 1 : 0;   // 1 = bf16 inputs/outputs
        int zeros = 0;
        for (int i = 1; i < 256; i += 2) if (eraw[i] == 0u) zeros++;
        flags[1] = (zeros >= 120) ? 1 : 0;  // 1 = int64 indices
    }
}

__device__ __forceinline__ float rd_f(const void* p, int j, bool bf) {
    return bf ? bf2f(((const unsigned short*)p)[j]) : ((const float*)p)[j];
}

// ---------- P1: canonicalize params: transposed bf16 weights + fp32 vectors ----------
__global__ void ingest_params(const void* W, const void* as, const void* ad, const void* bias,
                              const void* w1, const void* b1, const void* w2,
                              unsigned short* Wt, unsigned short* w1t,
                              float* asf, float* adf, float* biasf,
                              float* b1f, float* w2f,
                              const int* __restrict__ flags) {
    int i = blockIdx.x * 256 + threadIdx.x;
    bool bf = flags[0] != 0;
    if (i < 196608) {                              // Wt[p][n][k] = W[p][k][n]
        int p = i >> 16, n = (i >> 8) & 255, k = i & 255;
        Wt[i] = f2bf(rd_f(W, p * 65536 + k * 256 + n, bf));
    } else if (i < 229376) {                       // w1t[n][k] = w1[k][n]
        int j = i - 196608;
        int n = j >> 8, k = j & 255;
        w1t[j] = f2bf(rd_f(w1, k * 128 + n, bf));
    } else if (i < 230144) {
        int j = i - 229376; asf[j] = rd_f(as, j, bf);
    } else if (i < 230912) {
        int j = i - 230144; adf[j] = rd_f(ad, j, bf);
    } else if (i < 231680) {
        int j = i - 230912; biasf[j] = rd_f(bias, j, bf);
    } else if (i < 231808) {
        int j = i - 231680; b1f[j] = rd_f(b1, j, bf);
    } else if (i < 231936) {
        int j = i - 231808; w2f[j] = rd_f(w2, j, bf);
    }
}

// ---------- P2: canonicalize indices to int32 ----------
__global__ void ingest_idx(const void* e0, const void* e1, const void* e2,
                           int* __restrict__ dst, int twoE, const int* __restrict__ flags) {
    int i = blockIdx.x * 256 + threadIdx.x;
    if (i >= 3 * twoE) return;
    int p = i / twoE, j = i - p * twoE;
    const void* src = (p == 0) ? e0 : (p == 1) ? e1 : e2;
    int v = flags[1] ? (int)((const long long*)src)[j] : ((const int*)src)[j];
    dst[i] = v;
}

// ---------- K1: xw = h @ W[p]  (MFMA, wave = 16 rows x 128 cols) ----------
__global__ void gemm_xw_mfma(const void* __restrict__ h,
                             const unsigned short* __restrict__ Wtp, // [256(n),256(k)] bf16
                             unsigned short* __restrict__ xw,
                             const int* __restrict__ flags, int nrows) {
    int wave = blockIdx.x * 4 + (threadIdx.x >> 6);
    int rm = wave >> 1;          // 16-row tile
    int ch = wave & 1;           // which 128-col half
    if (rm * 16 >= nrows) return;
    int lane = threadIdx.x & 63;
    int l15 = lane & 15, quad = lane >> 4;
    bool bfm = flags[0] != 0;

    size_t rowoff = (size_t)(rm * 16 + l15) * 256 + quad * 8;
    const __bf16* wt = (const __bf16*)Wtp;

    f32x4 acc[8];
#pragma unroll
    for (int t = 0; t < 8; ++t) acc[t] = (f32x4){0.f, 0.f, 0.f, 0.f};

    for (int kc = 0; kc < 256; kc += 32) {
        bf16x8 a;
        if (bfm) {
            a = *reinterpret_cast<const bf16x8*>((const __bf16*)h + rowoff + kc);
        } else {
            f32x4 u0 = *reinterpret_cast<const f32x4*>((const float*)h + rowoff + kc);
            f32x4 u1 = *reinterpret_cast<const f32x4*>((const float*)h + rowoff + kc + 4);
#pragma unroll
            for (int j = 0; j < 4; ++j) { a[j] = (__bf16)u0[j]; a[4 + j] = (__bf16)u1[j]; }
        }
#pragma unroll
        for (int tn = 0; tn < 8; ++tn) {
            bf16x8 b = *reinterpret_cast<const bf16x8*>(
                wt + (size_t)(ch * 128 + tn * 16 + l15) * 256 + kc + quad * 8);
            acc[tn] = __builtin_amdgcn_mfma_f32_16x16x32_bf16(a, b, acc[tn], 0, 0, 0);
        }
    }
    // C/D: col = lane&15, row = quad*4 + reg
    int r0 = rm * 16 + quad * 4;
#pragma unroll
    for (int tn = 0; tn < 8; ++tn) {
        int c = ch * 128 + tn * 16 + l15;
#pragma unroll
        for (int i = 0; i < 4; ++i)
            xw[(size_t)(r0 + i) * 256 + c] = f2bf(acc[tn][i]);
    }
}

// ---------- K2: per-(n,h) attention logits + init m,s ----------
__global__ void alpha_kernel(const unsigned short* __restrict__ xw,
                             const float* __restrict__ att_src,
                             const float* __restrict__ att_dst,
                             float* __restrict__ as_, float* __restrict__ ad_,
                             unsigned int* __restrict__ mbuf, float* __restrict__ sbuf) {
    int n    = blockIdx.x;
    int wid  = threadIdx.x >> 6;
    int lane = threadIdx.x & 63;
    float x  = bf2f(xw[(size_t)n * 256 + wid * 64 + lane]);
    float vs = x * att_src[wid * 64 + lane];
    float vd = x * att_dst[wid * 64 + lane];
#pragma unroll
    for (int o = 32; o; o >>= 1) {
        vs += __shfl_down(vs, o);
        vd += __shfl_down(vd, o);
    }
    if (lane == 0) {
        int g = n * 4 + wid;
        as_[g] = vs;
        ad_[g] = vd;
        mbuf[g] = 0u;
        sbuf[g] = 0.f;
    }
}

__device__ __forceinline__ void edge_src_dst(const int* ei, int E, int e, int& src, int& dst) {
    if (e < E) { src = ei[e]; dst = ei[E + e]; }
    else       { src = dst = e - E; }
}
__device__ __forceinline__ float leaky(float v) { return v > 0.f ? v : 0.2f * v; }
__device__ __forceinline__ unsigned int fmap(float v) {
    unsigned int u = __float_as_uint(v);
    return (u & 0x80000000u) ? ~u : (u | 0x80000000u);
}
__device__ __forceinline__ float funmap(unsigned int u) {
    unsigned int b = (u & 0x80000000u) ? (u & 0x7fffffffu) : ~u;
    return __uint_as_float(b);
}

// ---------- K3: segment max ----------
__global__ void edge_max(const int* __restrict__ ei, int E, int N,
                         const float* __restrict__ as_, const float* __restrict__ ad_,
                         unsigned int* __restrict__ mbuf) {
    int idx = blockIdx.x * blockDim.x + threadIdx.x;
    if (idx >= (E + N) * 4) return;
    int e = idx >> 2, hh = idx & 3;
    int src, dst;
    edge_src_dst(ei, E, e, src, dst);
    float v = leaky(as_[src * 4 + hh] + ad_[dst * 4 + hh]);
    atomicMax(&mbuf[dst * 4 + hh], fmap(v));
}

// ---------- K4: segment sum of exp ----------
__global__ void edge_sum(const int* __restrict__ ei, int E, int N,
                         const float* __restrict__ as_, const float* __restrict__ ad_,
                         const unsigned int* __restrict__ mbuf, float* __restrict__ sbuf) {
    int idx = blockIdx.x * blockDim.x + threadIdx.x;
    if (idx >= (E + N) * 4) return;
    int e = idx >> 2, hh = idx & 3;
    int src, dst;
    edge_src_dst(ei, E, e, src, dst);
    float v  = leaky(as_[src * 4 + hh] + ad_[dst * 4 + hh]);
    float mf = funmap(mbuf[dst * 4 + hh]);
    atomicAdd(&sbuf[dst * 4 + hh], __expf(v - mf));
}

// ---------- K5: weighted aggregation into z[:,p,:] ----------
__global__ void edge_agg(const int* __restrict__ ei, int E, int N, int p,
                         const float* __restrict__ as_, const float* __restrict__ ad_,
                         const unsigned int* __restrict__ mbuf, const float* __restrict__ sbuf,
                         const unsigned short* __restrict__ xw, float* __restrict__ z) {
    int e = blockIdx.x;
    int t = threadIdx.x;
    int hh = t >> 6;
    int src, dst;
    edge_src_dst(ei, E, e, src, dst);
    float v     = leaky(as_[src * 4 + hh] + ad_[dst * 4 + hh]);
    float mf    = funmap(mbuf[dst * 4 + hh]);
    float alpha = __expf(v - mf) / sbuf[dst * 4 + hh];
    float x     = bf2f(xw[(size_t)src * 256 + t]);
    atomicAdd(&z[((size_t)dst * 3 + p) * 256 + t], alpha * x);
}

// ---------- K6: semantic attention via MFMA (wave = 16 rows x 128 hidden) ----------
__global__ void sem_w_mfma(const float* __restrict__ z,
                           const float* __restrict__ biasf,
                           const unsigned short* __restrict__ w1t,  // [128(n),256(k)] bf16
                           const float* __restrict__ b1f,
                           const float* __restrict__ w2f,
                           float* __restrict__ wsum, int rows) {
    __shared__ float part[3];
    if (threadIdx.x < 3) part[threadIdx.x] = 0.f;
    __syncthreads();

    int wave = blockIdx.x * 4 + (threadIdx.x >> 6);
    int lane = threadIdx.x & 63;
    int l15 = lane & 15, quad = lane >> 4;
    int row0 = wave * 16;
    const __bf16* wt = (const __bf16*)w1t;

    if (row0 < rows) {
        int q = row0 + l15;
        const float* zrow = z + (size_t)q * 256 + quad * 8;
        const float* brow = biasf + (q % 3) * 256 + quad * 8;

        f32x4 acc[8];
#pragma unroll
        for (int t = 0; t < 8; ++t) acc[t] = (f32x4){0.f, 0.f, 0.f, 0.f};

        for (int kc = 0; kc < 256; kc += 32) {
            f32x4 z0 = *reinterpret_cast<const f32x4*>(zrow + kc);
            f32x4 z1 = *reinterpret_cast<const f32x4*>(zrow + kc + 4);
            f32x4 b0 = *reinterpret_cast<const f32x4*>(brow + kc);
            f32x4 b1 = *reinterpret_cast<const f32x4*>(brow + kc + 4);
            bf16x8 a;
#pragma unroll
            for (int j = 0; j < 4; ++j) {
                a[j]     = (__bf16)(z0[j] + b0[j]);
                a[4 + j] = (__bf16)(z1[j] + b1[j]);
            }
#pragma unroll
            for (int tn = 0; tn < 8; ++tn) {
                bf16x8 b = *reinterpret_cast<const bf16x8*>(
                    wt + (size_t)(tn * 16 + l15) * 256 + kc + quad * 8);
                acc[tn] = __builtin_amdgcn_mfma_f32_16x16x32_bf16(a, b, acc[tn], 0, 0, 0);
            }
        }
        // epilogue: w[row] = sum_col tanh(acc + b1[col]) * w2[col]
        float rowsum[4] = {0.f, 0.f, 0.f, 0.f};
#pragma unroll
        for (int tn = 0; tn < 8; ++tn) {
            int col = tn * 16 + l15;
            float b1v = b1f[col], w2v = w2f[col];
#pragma unroll
            for (int i = 0; i < 4; ++i)
                rowsum[i] += tanhf(acc[tn][i] + b1v) * w2v;
        }
#pragma unroll
        for (int i = 0; i < 4; ++i) {
            rowsum[i] += __shfl_xor(rowsum[i], 1);
            rowsum[i] += __shfl_xor(rowsum[i], 2);
            rowsum[i] += __shfl_xor(rowsum[i], 4);
            rowsum[i] += __shfl_xor(rowsum[i], 8);
        }
        if (l15 == 0) {
#pragma unroll
            for (int i = 0; i < 4; ++i)
                atomicAdd(&part[(row0 + quad * 4 + i) % 3], rowsum[i]);
        }
    }
    __syncthreads();
    if (threadIdx.x < 3) atomicAdd(&wsum[threadIdx.x], part[threadIdx.x]);
}

// ---------- K7: beta = softmax(mean) ----------
__global__ void beta_kernel(const float* __restrict__ wsum, float* __restrict__ beta, float invN) {
    if (threadIdx.x == 0) {
        float w0 = wsum[0] * invN, w1 = wsum[1] * invN, w2 = wsum[2] * invN;
        float mx = fmaxf(w0, fmaxf(w1, w2));
        float e0 = __expf(w0 - mx), e1 = __expf(w1 - mx), e2 = __expf(w2 - mx);
        float s = e0 + e1 + e2;
        beta[0] = e0 / s; beta[1] = e1 / s; beta[2] = e2 / s;
    }
}

// ---------- K8: out = sum_p beta[p]*(z[:,p,:]+bias[p]) ----------
__global__ void combine(const float* __restrict__ z,
                        const float* __restrict__ biasf,
                        const float* __restrict__ beta,
                        void* __restrict__ out, const int* __restrict__ flags) {
    int idx = blockIdx.x * blockDim.x + threadIdx.x;
    int c = idx & 255;
    float b0 = beta[0], b1 = beta[1], b2 = beta[2];
    size_t base = (size_t)(idx >> 8) * 3 * 256 + c;
    float v = b0 * (z[base]       + biasf[c])
            + b1 * (z[base + 256] + biasf[256 + c])
            + b2 * (z[base + 512] + biasf[512 + c]);
    if (flags[0]) ((unsigned short*)out)[idx] = f2bf(v);
    else          ((float*)out)[idx] = v;
}

extern "C" void kernel_launch(void* const* d_in, const int* in_sizes, int n_in,
                              void* d_out, int out_size, void* d_ws, size_t ws_size,
                              hipStream_t stream) {
    const void* h    = d_in[0];
    const void* e0   = d_in[1];
    const void* e1   = d_in[2];
    const void* e2   = d_in[3];
    const void* W    = d_in[4];
    const void* as   = d_in[5];
    const void* ad   = d_in[6];
    const void* bias = d_in[7];
    const void* w1   = d_in[8];
    const void* b1   = d_in[9];
    const void* w2   = d_in[10];

    const int N = in_sizes[0] / 256;   // 50000
    const int E = in_sizes[1] / 2;     // 400000
    const int twoE = 2 * E;

    char* ws = (char*)d_ws;
    float*          z     = (float*)(ws + Z_OFF);
    unsigned short* xw    = (unsigned short*)(ws + XW_OFF);
    int*            eibuf = (int*)(ws + EI_OFF);
    float*          as_   = (float*)(ws + AS_OFF);
    float*          ad_   = (float*)(ws + AD_OFF);
    unsigned int*   mbuf  = (unsigned int*)(ws + M_OFF);
    float*          sbuf  = (float*)(ws + S_OFF);
    unsigned short* Wt    = (unsigned short*)(ws + WT_OFF);
    unsigned short* w1t   = (unsigned short*)(ws + W1T_OFF);
    float*          asf   = (float*)(ws + ASF_OFF);
    float*          adf   = (float*)(ws + ADF_OFF);
    float*          biasf = (float*)(ws + BIASF_OFF);
    float*          b1f   = (float*)(ws + B1F_OFF);
    float*          w2f   = (float*)(ws + W2F_OFF);
    float*          wsum  = (float*)(ws + WSUM_OFF);
    float*          beta  = (float*)(ws + BETA_OFF);
    int*            flags = (int*)(ws + FLAG_OFF);

    probe<<<1, 64, 0, stream>>>((const unsigned short*)h, (const unsigned int*)e0, flags);
    ingest_params<<<907, 256, 0, stream>>>(W, as, ad, bias, w1, b1, w2,
                                           Wt, w1t, asf, adf, biasf, b1f, w2f, flags);
    ingest_idx<<<(3 * twoE + 255) / 256, 256, 0, stream>>>(e0, e1, e2, eibuf, twoE, flags);

    hipMemsetAsync(z, 0, (size_t)N * 3 * 256 * sizeof(float), stream);
    hipMemsetAsync(wsum, 0, 16, stream);

    int edgeBlocks = ((E + N) * 4 + 255) / 256;
    int gemmBlocks = ((N / 16) * 2 + 3) / 4;       // 1563
    for (int p = 0; p < 3; ++p) {
        gemm_xw_mfma<<<gemmBlocks, 256, 0, stream>>>(h, Wt + p * 65536, xw, flags, N);
        alpha_kernel<<<N, 256, 0, stream>>>(xw, asf + p * 256, adf + p * 256,
                                            as_, ad_, mbuf, sbuf);
        const int* eip = eibuf + (size_t)p * twoE;
        edge_max<<<edgeBlocks, 256, 0, stream>>>(eip, E, N, as_, ad_, mbuf);
        edge_sum<<<edgeBlocks, 256, 0, stream>>>(eip, E, N, as_, ad_, mbuf, sbuf);
        edge_agg<<<E + N, 256, 0, stream>>>(eip, E, N, p, as_, ad_, mbuf, sbuf, xw, z);
    }

    int semBlocks = (3 * N / 16 + 3) / 4;          // 2344
    sem_w_mfma<<<semBlocks, 128, 0, stream>>>(z, biasf, w1t, b1f, w2f, wsum, 3 * N);
    beta_kernel<<<1, 64, 0, stream>>>(wsum, beta, 1.0f / (float)N);
    combine<<<N, 256, 0, stream>>>(z, biasf, beta, d_out, flags);
}

// Round 4
// 909.173 us; speedup vs baseline: 4.3953x; 1.9468x over previous
//
#include <hip/hip_runtime.h>
#include <hip/hip_bf16.h>

// ---------- helpers ----------
__device__ __forceinline__ float bf2f(unsigned short u) {
    union { unsigned int i; float f; } x;
    x.i = ((unsigned int)u) << 16;
    return x.f;
}
__device__ __forceinline__ unsigned short f2bf(float f) {
    union { float f; unsigned int u; } x; x.f = f;
    unsigned int r = x.u + 0x7FFFu + ((x.u >> 16) & 1u);
    return (unsigned short)(r >> 16);
}

typedef __bf16 bf16x8 __attribute__((ext_vector_type(8)));
typedef float  f32x4  __attribute__((ext_vector_type(4)));

// ---------- workspace byte offsets (total ~187.27 MB) ----------
#define Z_OFF      0UL            // N*3*256 f32 = 153,600,000
#define XW_OFF     153600000UL    // N*256 bf16  =  25,600,000
#define CSR_OFF    179200000UL    // 3*E int32   =   4,800,000
#define RS_OFF     184000000UL    // (3N+1) int32 row starts
#define CUR_OFF    184600064UL    // 3N int32 counters/cursors
#define BS_OFF     185200128UL    // 256 int32 block sums
#define AS_OFF     185201152UL    // N*4 f32
#define AD_OFF     186001152UL    // N*4 f32
#define WT_OFF     186801152UL    // 3*256*256 bf16 (transposed W)
#define W1T_OFF    187194368UL    // 128*256 bf16 (transposed w1)
#define ASF_OFF    187259904UL
#define ADF_OFF    187262976UL
#define BIASF_OFF  187266048UL
#define B1F_OFF    187269120UL
#define W2F_OFF    187269632UL
#define WSUM_OFF   187270144UL
#define BETA_OFF   187270208UL
#define FLAG_OFF   187270272UL

// ---------- P0: dtype probe ----------
__global__ void probe(const unsigned short* __restrict__ hraw,
                      const unsigned int* __restrict__ eraw,
                      int* __restrict__ flags) {
    if (threadIdx.x == 0 && blockIdx.x == 0) {
        int sane = 0;
        for (int i = 0; i < 256; ++i) {
            unsigned int e = (hraw[i] >> 7) & 0xFF;
            if (hraw[i] != 0 && e >= 100 && e <= 150) sane++;
        }
        flags[0] = (sane >= 220) ? 1 : 0;   // 1 = bf16 inputs/outputs
        int zeros = 0;
        for (int i = 1; i < 256; i += 2) if (eraw[i] == 0u) zeros++;
        flags[1] = (zeros >= 120) ? 1 : 0;  // 1 = int64 indices
    }
}

__device__ __forceinline__ float rd_f(const void* p, int j, bool bf) {
    return bf ? bf2f(((const unsigned short*)p)[j]) : ((const float*)p)[j];
}
__device__ __forceinline__ int rd_i(const void* p, long long j, bool i64) {
    return i64 ? (int)((const long long*)p)[j] : ((const int*)p)[j];
}

// ---------- P1: canonicalize params ----------
__global__ void ingest_params(const void* W, const void* as, const void* ad, const void* bias,
                              const void* w1, const void* b1, const void* w2,
                              unsigned short* Wt, unsigned short* w1t,
                              float* asf, float* adf, float* biasf,
                              float* b1f, float* w2f,
                              const int* __restrict__ flags) {
    int i = blockIdx.x * 256 + threadIdx.x;
    bool bf = flags[0] != 0;
    if (i < 196608) {                              // Wt[p][n][k] = W[p][k][n]
        int p = i >> 16, n = (i >> 8) & 255, k = i & 255;
        Wt[i] = f2bf(rd_f(W, p * 65536 + k * 256 + n, bf));
    } else if (i < 229376) {                       // w1t[n][k] = w1[k][n]
        int j = i - 196608;
        int n = j >> 8, k = j & 255;
        w1t[j] = f2bf(rd_f(w1, k * 128 + n, bf));
    } else if (i < 230144) {
        int j = i - 229376; asf[j] = rd_f(as, j, bf);
    } else if (i < 230912) {
        int j = i - 230144; adf[j] = rd_f(ad, j, bf);
    } else if (i < 231680) {
        int j = i - 230912; biasf[j] = rd_f(bias, j, bf);
    } else if (i < 231808) {
        int j = i - 231680; b1f[j] = rd_f(b1, j, bf);
    } else if (i < 231936) {
        int j = i - 231808; w2f[j] = rd_f(w2, j, bf);
    }
}

// ---------- CSR build ----------
__global__ void hist(const void* e0, const void* e1, const void* e2,
                     int* __restrict__ cnt, int E, int N, const int* __restrict__ flags) {
    int i = blockIdx.x * 256 + threadIdx.x;
    if (i >= 3 * E) return;
    int p = i / E, e = i - p * E;
    const void* ep = (p == 0) ? e0 : (p == 1) ? e1 : e2;
    int dst = rd_i(ep, (long long)E + e, flags[1] != 0);
    atomicAdd(&cnt[p * N + dst], 1);
}

__global__ void scan1(const int* __restrict__ cnt, int* __restrict__ rs,
                      int* __restrict__ bs, int M) {
    __shared__ int s[1024];
    int t = threadIdx.x, i = blockIdx.x * 1024 + t;
    int v = (i < M) ? cnt[i] : 0;
    s[t] = v; __syncthreads();
    for (int o = 1; o < 1024; o <<= 1) {
        int tmp = (t >= o) ? s[t - o] : 0;
        __syncthreads();
        s[t] += tmp;
        __syncthreads();
    }
    if (i < M) rs[i] = s[t] - v;               // exclusive within block
    if (t == 1023) bs[blockIdx.x] = s[t];      // block total
}

__global__ void scan2(int* __restrict__ bs, int* __restrict__ rs, int nb, int M) {
    __shared__ int s[256];
    int t = threadIdx.x;
    int v = (t < nb) ? bs[t] : 0;
    s[t] = v; __syncthreads();
    for (int o = 1; o < 256; o <<= 1) {
        int tmp = (t >= o) ? s[t - o] : 0;
        __syncthreads();
        s[t] += tmp;
        __syncthreads();
    }
    if (t < nb) bs[t] = s[t] - v;              // exclusive block offsets
    if (t == nb - 1) rs[M] = s[t];             // grand total
}

__global__ void scan3(int* __restrict__ rs, const int* __restrict__ bs, int M) {
    int i = blockIdx.x * 1024 + threadIdx.x;
    if (i < M) rs[i] += bs[blockIdx.x];
}

__global__ void scatter(const void* e0, const void* e1, const void* e2,
                        const int* __restrict__ rs, int* __restrict__ cur,
                        int* __restrict__ csr, int E, int N,
                        const int* __restrict__ flags) {
    int i = blockIdx.x * 256 + threadIdx.x;
    if (i >= 3 * E) return;
    int p = i / E, e = i - p * E;
    const void* ep = (p == 0) ? e0 : (p == 1) ? e1 : e2;
    bool i64 = flags[1] != 0;
    int src = rd_i(ep, e, i64);
    int dst = rd_i(ep, (long long)E + e, i64);
    int seg = p * N + dst;
    int pos = rs[seg] + atomicAdd(&cur[seg], 1);
    csr[pos] = src;
}

// ---------- K1: xw = h @ W[p]  (MFMA, wave = 16 rows x 128 cols) ----------
__global__ void gemm_xw_mfma(const void* __restrict__ h,
                             const unsigned short* __restrict__ Wtp,
                             unsigned short* __restrict__ xw,
                             const int* __restrict__ flags, int nrows) {
    int wave = blockIdx.x * 4 + (threadIdx.x >> 6);
    int rm = wave >> 1;
    int ch = wave & 1;
    if (rm * 16 >= nrows) return;
    int lane = threadIdx.x & 63;
    int l15 = lane & 15, quad = lane >> 4;
    bool bfm = flags[0] != 0;

    size_t rowoff = (size_t)(rm * 16 + l15) * 256 + quad * 8;
    const __bf16* wt = (const __bf16*)Wtp;

    f32x4 acc[8];
#pragma unroll
    for (int t = 0; t < 8; ++t) acc[t] = (f32x4){0.f, 0.f, 0.f, 0.f};

    for (int kc = 0; kc < 256; kc += 32) {
        bf16x8 a;
        if (bfm) {
            a = *reinterpret_cast<const bf16x8*>((const __bf16*)h + rowoff + kc);
        } else {
            f32x4 u0 = *reinterpret_cast<const f32x4*>((const float*)h + rowoff + kc);
            f32x4 u1 = *reinterpret_cast<const f32x4*>((const float*)h + rowoff + kc + 4);
#pragma unroll
            for (int j = 0; j < 4; ++j) { a[j] = (__bf16)u0[j]; a[4 + j] = (__bf16)u1[j]; }
        }
#pragma unroll
        for (int tn = 0; tn < 8; ++tn) {
            bf16x8 b = *reinterpret_cast<const bf16x8*>(
                wt + (size_t)(ch * 128 + tn * 16 + l15) * 256 + kc + quad * 8);
            acc[tn] = __builtin_amdgcn_mfma_f32_16x16x32_bf16(a, b, acc[tn], 0, 0, 0);
        }
    }
    int r0 = rm * 16 + quad * 4;
#pragma unroll
    for (int tn = 0; tn < 8; ++tn) {
        int c = ch * 128 + tn * 16 + l15;
#pragma unroll
        for (int i = 0; i < 4; ++i)
            xw[(size_t)(r0 + i) * 256 + c] = f2bf(acc[tn][i]);
    }
}

// ---------- K2: per-(n,h) attention logits ----------
__global__ void alpha_kernel(const unsigned short* __restrict__ xw,
                             const float* __restrict__ att_src,
                             const float* __restrict__ att_dst,
                             float* __restrict__ as_, float* __restrict__ ad_) {
    int n    = blockIdx.x;
    int wid  = threadIdx.x >> 6;
    int lane = threadIdx.x & 63;
    float x  = bf2f(xw[(size_t)n * 256 + wid * 64 + lane]);
    float vs = x * att_src[wid * 64 + lane];
    float vd = x * att_dst[wid * 64 + lane];
#pragma unroll
    for (int o = 32; o; o >>= 1) {
        vs += __shfl_down(vs, o);
        vd += __shfl_down(vd, o);
    }
    if (lane == 0) {
        int g = n * 4 + wid;
        as_[g] = vs;
        ad_[g] = vd;
    }
}

__device__ __forceinline__ float leaky(float v) { return v > 0.f ? v : 0.2f * v; }

// ---------- K5: CSR softmax + aggregate (one wave per dst) ----------
__global__ void agg_csr(const int* __restrict__ csr, const int* __restrict__ rs,
                        const float* __restrict__ as_, const float* __restrict__ ad_,
                        const unsigned short* __restrict__ xw, float* __restrict__ z,
                        int N, int p) {
    int d = blockIdx.x * 4 + (threadIdx.x >> 6);
    if (d >= N) return;
    int lane = threadIdx.x & 63;
    int h = lane >> 4;
    int seg = p * N + d;
    int start = rs[seg], end = rs[seg + 1];

    float adh   = ad_[d * 4 + h];
    float vself = leaky(as_[d * 4 + h] + adh);
    float m = vself;
    for (int j = start; j < end; ++j) {
        int src = csr[j];
        float v = leaky(as_[src * 4 + h] + adh);
        m = fmaxf(m, v);
    }
    float l = 0.f;
    float a0 = 0.f, a1 = 0.f, a2 = 0.f, a3 = 0.f;
    for (int j = start; j < end; ++j) {
        int src = csr[j];
        float v  = leaky(as_[src * 4 + h] + adh);
        float wj = __expf(v - m);
        l += wj;
        ushort4 u = *reinterpret_cast<const ushort4*>(xw + (size_t)src * 256 + lane * 4);
        a0 += wj * bf2f(u.x); a1 += wj * bf2f(u.y);
        a2 += wj * bf2f(u.z); a3 += wj * bf2f(u.w);
    }
    {
        float ws = __expf(vself - m);
        l += ws;
        ushort4 u = *reinterpret_cast<const ushort4*>(xw + (size_t)d * 256 + lane * 4);
        a0 += ws * bf2f(u.x); a1 += ws * bf2f(u.y);
        a2 += ws * bf2f(u.z); a3 += ws * bf2f(u.w);
    }
    float inv = 1.f / l;
    f32x4 o = {a0 * inv, a1 * inv, a2 * inv, a3 * inv};
    *reinterpret_cast<f32x4*>(&z[((size_t)d * 3 + p) * 256 + lane * 4]) = o;
}

// ---------- K6: semantic attention via MFMA (wave = 16 rows x 128 hidden) ----------
__global__ void sem_w_mfma(const float* __restrict__ z,
                           const float* __restrict__ biasf,
                           const unsigned short* __restrict__ w1t,
                           const float* __restrict__ b1f,
                           const float* __restrict__ w2f,
                           float* __restrict__ wsum, int rows) {
    __shared__ float part[3];
    if (threadIdx.x < 3) part[threadIdx.x] = 0.f;
    __syncthreads();

    int wave = blockIdx.x * 4 + (threadIdx.x >> 6);
    int lane = threadIdx.x & 63;
    int l15 = lane & 15, quad = lane >> 4;
    int row0 = wave * 16;
    const __bf16* wt = (const __bf16*)w1t;

    if (row0 < rows) {
        int q = row0 + l15;
        const float* zrow = z + (size_t)q * 256 + quad * 8;
        const float* brow = biasf + (q % 3) * 256 + quad * 8;

        f32x4 acc[8];
#pragma unroll
        for (int t = 0; t < 8; ++t) acc[t] = (f32x4){0.f, 0.f, 0.f, 0.f};

        for (int kc = 0; kc < 256; kc += 32) {
            f32x4 z0 = *reinterpret_cast<const f32x4*>(zrow + kc);
            f32x4 z1 = *reinterpret_cast<const f32x4*>(zrow + kc + 4);
            f32x4 b0 = *reinterpret_cast<const f32x4*>(brow + kc);
            f32x4 b1 = *reinterpret_cast<const f32x4*>(brow + kc + 4);
            bf16x8 a;
#pragma unroll
            for (int j = 0; j < 4; ++j) {
                a[j]     = (__bf16)(z0[j] + b0[j]);
                a[4 + j] = (__bf16)(z1[j] + b1[j]);
            }
#pragma unroll
            for (int tn = 0; tn < 8; ++tn) {
                bf16x8 b = *reinterpret_cast<const bf16x8*>(
                    wt + (size_t)(tn * 16 + l15) * 256 + kc + quad * 8);
                acc[tn] = __builtin_amdgcn_mfma_f32_16x16x32_bf16(a, b, acc[tn], 0, 0, 0);
            }
        }
        float rowsum[4] = {0.f, 0.f, 0.f, 0.f};
#pragma unroll
        for (int tn = 0; tn < 8; ++tn) {
            int col = tn * 16 + l15;
            float b1v = b1f[col], w2v = w2f[col];
#pragma unroll
            for (int i = 0; i < 4; ++i)
                rowsum[i] += tanhf(acc[tn][i] + b1v) * w2v;
        }
#pragma unroll
        for (int i = 0; i < 4; ++i) {
            rowsum[i] += __shfl_xor(rowsum[i], 1);
            rowsum[i] += __shfl_xor(rowsum[i], 2);
            rowsum[i] += __shfl_xor(rowsum[i], 4);
            rowsum[i] += __shfl_xor(rowsum[i], 8);
        }
        if (l15 == 0) {
#pragma unroll
            for (int i = 0; i < 4; ++i)
                atomicAdd(&part[(row0 + quad * 4 + i) % 3], rowsum[i]);
        }
    }
    __syncthreads();
    if (threadIdx.x < 3) atomicAdd(&wsum[threadIdx.x], part[threadIdx.x]);
}

// ---------- K7: beta = softmax(mean) ----------
__global__ void beta_kernel(const float* __restrict__ wsum, float* __restrict__ beta, float invN) {
    if (threadIdx.x == 0) {
        float w0 = wsum[0] * invN, w1 = wsum[1] * invN, w2 = wsum[2] * invN;
        float mx = fmaxf(w0, fmaxf(w1, w2));
        float e0 = __expf(w0 - mx), e1 = __expf(w1 - mx), e2 = __expf(w2 - mx);
        float s = e0 + e1 + e2;
        beta[0] = e0 / s; beta[1] = e1 / s; beta[2] = e2 / s;
    }
}

// ---------- K8: out = sum_p beta[p]*(z[:,p,:]+bias[p]) ----------
__global__ void combine(const float* __restrict__ z,
                        const float* __restrict__ biasf,
                        const float* __restrict__ beta,
                        void* __restrict__ out, const int* __restrict__ flags) {
    int idx = blockIdx.x * blockDim.x + threadIdx.x;
    int c = idx & 255;
    float b0 = beta[0], b1 = beta[1], b2 = beta[2];
    size_t base = (size_t)(idx >> 8) * 3 * 256 + c;
    float v = b0 * (z[base]       + biasf[c])
            + b1 * (z[base + 256] + biasf[256 + c])
            + b2 * (z[base + 512] + biasf[512 + c]);
    if (flags[0]) ((unsigned short*)out)[idx] = f2bf(v);
    else          ((float*)out)[idx] = v;
}

extern "C" void kernel_launch(void* const* d_in, const int* in_sizes, int n_in,
                              void* d_out, int out_size, void* d_ws, size_t ws_size,
                              hipStream_t stream) {
    const void* h    = d_in[0];
    const void* e0   = d_in[1];
    const void* e1   = d_in[2];
    const void* e2   = d_in[3];
    const void* W    = d_in[4];
    const void* as   = d_in[5];
    const void* ad   = d_in[6];
    const void* bias = d_in[7];
    const void* w1   = d_in[8];
    const void* b1   = d_in[9];
    const void* w2   = d_in[10];

    const int N = in_sizes[0] / 256;   // 50000
    const int E = in_sizes[1] / 2;     // 400000
    const int M = 3 * N;               // 150000 segments

    char* ws = (char*)d_ws;
    float*          z     = (float*)(ws + Z_OFF);
    unsigned short* xw    = (unsigned short*)(ws + XW_OFF);
    int*            csr   = (int*)(ws + CSR_OFF);
    int*            rs    = (int*)(ws + RS_OFF);
    int*            cur   = (int*)(ws + CUR_OFF);
    int*            bs    = (int*)(ws + BS_OFF);
    float*          as_   = (float*)(ws + AS_OFF);
    float*          ad_   = (float*)(ws + AD_OFF);
    unsigned short* Wt    = (unsigned short*)(ws + WT_OFF);
    unsigned short* w1t   = (unsigned short*)(ws + W1T_OFF);
    float*          asf   = (float*)(ws + ASF_OFF);
    float*          adf   = (float*)(ws + ADF_OFF);
    float*          biasf = (float*)(ws + BIASF_OFF);
    float*          b1f   = (float*)(ws + B1F_OFF);
    float*          w2f   = (float*)(ws + W2F_OFF);
    float*          wsum  = (float*)(ws + WSUM_OFF);
    float*          beta  = (float*)(ws + BETA_OFF);
    int*            flags = (int*)(ws + FLAG_OFF);

    probe<<<1, 64, 0, stream>>>((const unsigned short*)h, (const unsigned int*)e0, flags);
    ingest_params<<<907, 256, 0, stream>>>(W, as, ad, bias, w1, b1, w2,
                                           Wt, w1t, asf, adf, biasf, b1f, w2f, flags);

    // CSR build (all 3 paths)
    int nb = (M + 1023) / 1024;                    // 147
    int eB = (3 * E + 255) / 256;                  // 4688
    hipMemsetAsync(cur, 0, M * sizeof(int), stream);
    hist<<<eB, 256, 0, stream>>>(e0, e1, e2, cur, E, N, flags);
    scan1<<<nb, 1024, 0, stream>>>(cur, rs, bs, M);
    scan2<<<1, 256, 0, stream>>>(bs, rs, nb, M);
    scan3<<<nb, 1024, 0, stream>>>(rs, bs, M);
    hipMemsetAsync(cur, 0, M * sizeof(int), stream);
    scatter<<<eB, 256, 0, stream>>>(e0, e1, e2, rs, cur, csr, E, N, flags);

    hipMemsetAsync(wsum, 0, 16, stream);

    int gemmBlocks = ((N / 16) * 2 + 3) / 4;       // 1563
    int aggBlocks  = (N + 3) / 4;                  // 12500
    for (int p = 0; p < 3; ++p) {
        gemm_xw_mfma<<<gemmBlocks, 256, 0, stream>>>(h, Wt + p * 65536, xw, flags, N);
        alpha_kernel<<<N, 256, 0, stream>>>(xw, asf + p * 256, adf + p * 256, as_, ad_);
        agg_csr<<<aggBlocks, 256, 0, stream>>>(csr, rs, as_, ad_, xw, z, N, p);
    }

    int semBlocks = (M / 16 + 3) / 4;              // 2344
    sem_w_mfma<<<semBlocks, 256, 0, stream>>>(z, biasf, w1t, b1f, w2f, wsum, M);
    beta_kernel<<<1, 64, 0, stream>>>(wsum, beta, 1.0f / (float)N);
    combine<<<N, 256, 0, stream>>>(z, biasf, beta, d_out, flags);
}

// Round 5
// 742.779 us; speedup vs baseline: 5.3799x; 1.2240x over previous
//
#include <hip/hip_runtime.h>
#include <hip/hip_bf16.h>

// ---------- helpers ----------
__device__ __forceinline__ float bf2f(unsigned short u) {
    union { unsigned int i; float f; } x;
    x.i = ((unsigned int)u) << 16;
    return x.f;
}
__device__ __forceinline__ unsigned short f2bf(float f) {
    union { float f; unsigned int u; } x; x.f = f;
    unsigned int r = x.u + 0x7FFFu + ((x.u >> 16) & 1u);
    return (unsigned short)(r >> 16);
}

typedef __bf16    bf16x8 __attribute__((ext_vector_type(8)));
typedef _Float16  f16x8  __attribute__((ext_vector_type(8)));
typedef _Float16  f16x4  __attribute__((ext_vector_type(4)));
typedef float     f32x4  __attribute__((ext_vector_type(4)));

// ---------- workspace byte offsets (total ~110.5 MB) ----------
#define XW_OFF     0UL            // N*256 bf16      = 25,600,000
#define ZB_OFF     25600000UL     // 3N*256 f16      = 76,800,000 (bias folded)
#define CSR_OFF    102400000UL    // 3E int32        =  4,800,000
#define RS_OFF     107200000UL    // (3N+1) int32
#define CUR_OFF    107800064UL    // 3N int32
#define BS_OFF     108400128UL    // 256 int32
#define AS_OFF     108401152UL    // N*4 f32
#define AD_OFF     109201152UL    // N*4 f32
#define WT_OFF     110001152UL    // 3*256*256 bf16 (transposed W)
#define W1T_OFF    110394368UL    // 128*256 f16 (transposed w1)
#define ASF_OFF    110459904UL    // 768 f32
#define ADF_OFF    110462976UL
#define BIASF_OFF  110466048UL
#define B1F_OFF    110469120UL
#define W2F_OFF    110469632UL
#define WSUM_OFF   110470144UL
#define BETA_OFF   110470208UL
#define FLAG_OFF   110470272UL

// ---------- P0: dtype probe ----------
__global__ void probe(const unsigned short* __restrict__ hraw,
                      const unsigned int* __restrict__ eraw,
                      int* __restrict__ flags) {
    if (threadIdx.x == 0 && blockIdx.x == 0) {
        int sane = 0;
        for (int i = 0; i < 256; ++i) {
            unsigned int e = (hraw[i] >> 7) & 0xFF;
            if (hraw[i] != 0 && e >= 100 && e <= 150) sane++;
        }
        flags[0] = (sane >= 220) ? 1 : 0;   // 1 = bf16 inputs/outputs
        int zeros = 0;
        for (int i = 1; i < 256; i += 2) if (eraw[i] == 0u) zeros++;
        flags[1] = (zeros >= 120) ? 1 : 0;  // 1 = int64 indices
    }
}

__device__ __forceinline__ float rd_f(const void* p, int j, bool bf) {
    return bf ? bf2f(((const unsigned short*)p)[j]) : ((const float*)p)[j];
}
__device__ __forceinline__ int rd_i(const void* p, long long j, bool i64) {
    return i64 ? (int)((const long long*)p)[j] : ((const int*)p)[j];
}

// ---------- P1: canonicalize params ----------
__global__ void ingest_params(const void* W, const void* as, const void* ad, const void* bias,
                              const void* w1, const void* b1, const void* w2,
                              unsigned short* Wt, _Float16* w1t,
                              float* asf, float* adf, float* biasf,
                              float* b1f, float* w2f,
                              const int* __restrict__ flags) {
    int i = blockIdx.x * 256 + threadIdx.x;
    bool bf = flags[0] != 0;
    if (i < 196608) {                              // Wt[p][n][k] = W[p][k][n]
        int p = i >> 16, n = (i >> 8) & 255, k = i & 255;
        Wt[i] = f2bf(rd_f(W, p * 65536 + k * 256 + n, bf));
    } else if (i < 229376) {                       // w1t[n][k] = w1[k][n], fp16
        int j = i - 196608;
        int n = j >> 8, k = j & 255;
        w1t[j] = (_Float16)rd_f(w1, k * 128 + n, bf);
    } else if (i < 230144) {
        int j = i - 229376; asf[j] = rd_f(as, j, bf);
    } else if (i < 230912) {
        int j = i - 230144; adf[j] = rd_f(ad, j, bf);
    } else if (i < 231680) {
        int j = i - 230912; biasf[j] = rd_f(bias, j, bf);
    } else if (i < 231808) {
        int j = i - 231680; b1f[j] = rd_f(b1, j, bf);
    } else if (i < 231936) {
        int j = i - 231808; w2f[j] = rd_f(w2, j, bf);
    }
}

// ---------- CSR build ----------
__global__ void hist(const void* e0, const void* e1, const void* e2,
                     int* __restrict__ cnt, int E, int N, const int* __restrict__ flags) {
    int i = blockIdx.x * 256 + threadIdx.x;
    if (i >= 3 * E) return;
    int p = i / E, e = i - p * E;
    const void* ep = (p == 0) ? e0 : (p == 1) ? e1 : e2;
    int dst = rd_i(ep, (long long)E + e, flags[1] != 0);
    atomicAdd(&cnt[p * N + dst], 1);
}

__global__ void scan1(const int* __restrict__ cnt, int* __restrict__ rs,
                      int* __restrict__ bs, int M) {
    __shared__ int s[1024];
    int t = threadIdx.x, i = blockIdx.x * 1024 + t;
    int v = (i < M) ? cnt[i] : 0;
    s[t] = v; __syncthreads();
    for (int o = 1; o < 1024; o <<= 1) {
        int tmp = (t >= o) ? s[t - o] : 0;
        __syncthreads();
        s[t] += tmp;
        __syncthreads();
    }
    if (i < M) rs[i] = s[t] - v;
    if (t == 1023) bs[blockIdx.x] = s[t];
}

__global__ void scan2(int* __restrict__ bs, int* __restrict__ rs, int nb, int M) {
    __shared__ int s[256];
    int t = threadIdx.x;
    int v = (t < nb) ? bs[t] : 0;
    s[t] = v; __syncthreads();
    for (int o = 1; o < 256; o <<= 1) {
        int tmp = (t >= o) ? s[t - o] : 0;
        __syncthreads();
        s[t] += tmp;
        __syncthreads();
    }
    if (t < nb) bs[t] = s[t] - v;
    if (t == nb - 1) rs[M] = s[t];
}

__global__ void scan3(int* __restrict__ rs, const int* __restrict__ bs, int M) {
    int i = blockIdx.x * 1024 + threadIdx.x;
    if (i < M) rs[i] += bs[blockIdx.x];
}

__global__ void scatter(const void* e0, const void* e1, const void* e2,
                        const int* __restrict__ rs, int* __restrict__ cur,
                        int* __restrict__ csr, int E, int N,
                        const int* __restrict__ flags) {
    int i = blockIdx.x * 256 + threadIdx.x;
    if (i >= 3 * E) return;
    int p = i / E, e = i - p * E;
    const void* ep = (p == 0) ? e0 : (p == 1) ? e1 : e2;
    bool i64 = flags[1] != 0;
    int src = rd_i(ep, e, i64);
    int dst = rd_i(ep, (long long)E + e, i64);
    int seg = p * N + dst;
    int pos = rs[seg] + atomicAdd(&cur[seg], 1);
    csr[pos] = src;
}

// ---------- K1: xw = h @ W[p] (MFMA) + fused alpha epilogue ----------
__global__ void gemm_xw_mfma(const void* __restrict__ h,
                             const unsigned short* __restrict__ Wtp,
                             unsigned short* __restrict__ xw,
                             const float* __restrict__ asf,   // [256] this path
                             const float* __restrict__ adf,
                             float* __restrict__ as_, float* __restrict__ ad_,
                             const int* __restrict__ flags, int nrows) {
    int wave = blockIdx.x * 4 + (threadIdx.x >> 6);
    int rm = wave >> 1;
    int ch = wave & 1;
    if (rm * 16 >= nrows) return;
    int lane = threadIdx.x & 63;
    int l15 = lane & 15, quad = lane >> 4;
    bool bfm = flags[0] != 0;

    size_t rowoff = (size_t)(rm * 16 + l15) * 256 + quad * 8;
    const __bf16* wt = (const __bf16*)Wtp;

    f32x4 acc[8];
#pragma unroll
    for (int t = 0; t < 8; ++t) acc[t] = (f32x4){0.f, 0.f, 0.f, 0.f};

    for (int kc = 0; kc < 256; kc += 32) {
        bf16x8 a;
        if (bfm) {
            a = *reinterpret_cast<const bf16x8*>((const __bf16*)h + rowoff + kc);
        } else {
            f32x4 u0 = *reinterpret_cast<const f32x4*>((const float*)h + rowoff + kc);
            f32x4 u1 = *reinterpret_cast<const f32x4*>((const float*)h + rowoff + kc + 4);
#pragma unroll
            for (int j = 0; j < 4; ++j) { a[j] = (__bf16)u0[j]; a[4 + j] = (__bf16)u1[j]; }
        }
#pragma unroll
        for (int tn = 0; tn < 8; ++tn) {
            bf16x8 b = *reinterpret_cast<const bf16x8*>(
                wt + (size_t)(ch * 128 + tn * 16 + l15) * 256 + kc + quad * 8);
            acc[tn] = __builtin_amdgcn_mfma_f32_16x16x32_bf16(a, b, acc[tn], 0, 0, 0);
        }
    }
    // store xw (C/D: col = lane&15, row = quad*4 + reg)
    int r0 = rm * 16 + quad * 4;
#pragma unroll
    for (int tn = 0; tn < 8; ++tn) {
        int c = ch * 128 + tn * 16 + l15;
#pragma unroll
        for (int i = 0; i < 4; ++i)
            xw[(size_t)(r0 + i) * 256 + c] = f2bf(acc[tn][i]);
    }
    // fused alpha: this wave owns heads {ch*2, ch*2+1} fully (cols ch*128..ch*128+127)
    float ss[2][4] = {{0.f,0.f,0.f,0.f},{0.f,0.f,0.f,0.f}};
    float dd[2][4] = {{0.f,0.f,0.f,0.f},{0.f,0.f,0.f,0.f}};
#pragma unroll
    for (int tn = 0; tn < 8; ++tn) {
        int col = ch * 128 + tn * 16 + l15;
        float sv = asf[col], dv = adf[col];
        int hs = tn >> 2;
#pragma unroll
        for (int i = 0; i < 4; ++i) {
            ss[hs][i] += acc[tn][i] * sv;
            dd[hs][i] += acc[tn][i] * dv;
        }
    }
#pragma unroll
    for (int hs = 0; hs < 2; ++hs)
#pragma unroll
        for (int i = 0; i < 4; ++i) {
            float s = ss[hs][i], d = dd[hs][i];
            s += __shfl_xor(s, 1); d += __shfl_xor(d, 1);
            s += __shfl_xor(s, 2); d += __shfl_xor(d, 2);
            s += __shfl_xor(s, 4); d += __shfl_xor(d, 4);
            s += __shfl_xor(s, 8); d += __shfl_xor(d, 8);
            ss[hs][i] = s; dd[hs][i] = d;
        }
    if (l15 == 0) {
#pragma unroll
        for (int hs = 0; hs < 2; ++hs)
#pragma unroll
            for (int i = 0; i < 4; ++i) {
                int g = (r0 + i) * 4 + ch * 2 + hs;
                as_[g] = ss[hs][i];
                ad_[g] = dd[hs][i];
            }
    }
}

__device__ __forceinline__ float leaky(float v) { return v > 0.f ? v : 0.2f * v; }

// ---------- K5: CSR online-softmax aggregate -> z' fp16 (bias folded) ----------
__global__ void agg_csr(const int* __restrict__ csr, const int* __restrict__ rs,
                        const float* __restrict__ as_, const float* __restrict__ ad_,
                        const unsigned short* __restrict__ xw,
                        const float* __restrict__ biasf,
                        _Float16* __restrict__ zb, int N, int p) {
    int d = blockIdx.x * 4 + (threadIdx.x >> 6);
    if (d >= N) return;
    int lane = threadIdx.x & 63;
    int h = lane >> 4;                 // 4 cols per lane -> head = (lane*4)>>6
    int seg = p * N + d;
    int start = rs[seg], end = rs[seg + 1];

    float adh = ad_[d * 4 + h];
    // init with self-loop
    float m = leaky(as_[d * 4 + h] + adh);
    float l = 1.f;
    float a0, a1, a2, a3;
    {
        ushort4 u = *reinterpret_cast<const ushort4*>(xw + (size_t)d * 256 + lane * 4);
        a0 = bf2f(u.x); a1 = bf2f(u.y); a2 = bf2f(u.z); a3 = bf2f(u.w);
    }
    int srcA = (start < end) ? csr[start] : 0;
    for (int j = start; j < end; ++j) {
        int srcB = (j + 1 < end) ? csr[j + 1] : 0;
        float v = leaky(as_[srcA * 4 + h] + adh);
        ushort4 u = *reinterpret_cast<const ushort4*>(xw + (size_t)srcA * 256 + lane * 4);
        float mn = fmaxf(m, v);
        float c = __expf(m - mn);
        float w = __expf(v - mn);
        m = mn;
        l = l * c + w;
        a0 = a0 * c + w * bf2f(u.x);
        a1 = a1 * c + w * bf2f(u.y);
        a2 = a2 * c + w * bf2f(u.z);
        a3 = a3 * c + w * bf2f(u.w);
        srcA = srcB;
    }
    float inv = 1.f / l;
    int col = lane * 4;
    const float* bp = biasf + p * 256 + col;
    f16x4 o = {(_Float16)(a0 * inv + bp[0]), (_Float16)(a1 * inv + bp[1]),
               (_Float16)(a2 * inv + bp[2]), (_Float16)(a3 * inv + bp[3])};
    *reinterpret_cast<f16x4*>(zb + ((size_t)d * 3 + p) * 256 + col) = o;
}

// ---------- K6: semantic attention via f16 MFMA ----------
__global__ void sem_w_mfma(const _Float16* __restrict__ zb,
                           const _Float16* __restrict__ w1t,   // [128,256] f16
                           const float* __restrict__ b1f,
                           const float* __restrict__ w2f,
                           float* __restrict__ wsum, int rows) {
    __shared__ float part[3];
    if (threadIdx.x < 3) part[threadIdx.x] = 0.f;
    __syncthreads();

    int wave = blockIdx.x * 4 + (threadIdx.x >> 6);
    int lane = threadIdx.x & 63;
    int l15 = lane & 15, quad = lane >> 4;
    int row0 = wave * 16;

    if (row0 < rows) {
        int q = row0 + l15;
        const _Float16* zrow = zb + (size_t)q * 256 + quad * 8;

        f32x4 acc[8];
#pragma unroll
        for (int t = 0; t < 8; ++t) acc[t] = (f32x4){0.f, 0.f, 0.f, 0.f};

#pragma unroll
        for (int kc = 0; kc < 256; kc += 32) {
            f16x8 a = *reinterpret_cast<const f16x8*>(zrow + kc);
#pragma unroll
            for (int tn = 0; tn < 8; ++tn) {
                f16x8 b = *reinterpret_cast<const f16x8*>(
                    w1t + (size_t)(tn * 16 + l15) * 256 + kc + quad * 8);
                acc[tn] = __builtin_amdgcn_mfma_f32_16x16x32_f16(a, b, acc[tn], 0, 0, 0);
            }
        }
        float rowsum[4] = {0.f, 0.f, 0.f, 0.f};
#pragma unroll
        for (int tn = 0; tn < 8; ++tn) {
            int col = tn * 16 + l15;
            float b1v = b1f[col], w2v = w2f[col];
#pragma unroll
            for (int i = 0; i < 4; ++i)
                rowsum[i] += tanhf(acc[tn][i] + b1v) * w2v;
        }
#pragma unroll
        for (int i = 0; i < 4; ++i) {
            rowsum[i] += __shfl_xor(rowsum[i], 1);
            rowsum[i] += __shfl_xor(rowsum[i], 2);
            rowsum[i] += __shfl_xor(rowsum[i], 4);
            rowsum[i] += __shfl_xor(rowsum[i], 8);
        }
        if (l15 == 0) {
#pragma unroll
            for (int i = 0; i < 4; ++i)
                atomicAdd(&part[(row0 + quad * 4 + i) % 3], rowsum[i]);
        }
    }
    __syncthreads();
    if (threadIdx.x < 3) atomicAdd(&wsum[threadIdx.x], part[threadIdx.x]);
}

// ---------- K7: beta = softmax(mean) ----------
__global__ void beta_kernel(const float* __restrict__ wsum, float* __restrict__ beta, float invN) {
    if (threadIdx.x == 0) {
        float w0 = wsum[0] * invN, w1 = wsum[1] * invN, w2 = wsum[2] * invN;
        float mx = fmaxf(w0, fmaxf(w1, w2));
        float e0 = __expf(w0 - mx), e1 = __expf(w1 - mx), e2 = __expf(w2 - mx);
        float s = e0 + e1 + e2;
        beta[0] = e0 / s; beta[1] = e1 / s; beta[2] = e2 / s;
    }
}

// ---------- K8: out = sum_p beta[p]*z'[:,p,:] (bias already folded) ----------
__global__ void combine(const _Float16* __restrict__ zb,
                        const float* __restrict__ beta,
                        void* __restrict__ out, const int* __restrict__ flags) {
    int idx = blockIdx.x * 256 + threadIdx.x;    // over N*64
    int n = idx >> 6, c4 = (idx & 63) * 4;
    float b0 = beta[0], b1 = beta[1], b2 = beta[2];
    const _Float16* base = zb + (size_t)n * 768 + c4;
    f16x4 z0 = *reinterpret_cast<const f16x4*>(base);
    f16x4 z1 = *reinterpret_cast<const f16x4*>(base + 256);
    f16x4 z2 = *reinterpret_cast<const f16x4*>(base + 512);
    float v[4];
#pragma unroll
    for (int i = 0; i < 4; ++i)
        v[i] = b0 * (float)z0[i] + b1 * (float)z1[i] + b2 * (float)z2[i];
    if (flags[0]) {
        ushort4 o = {f2bf(v[0]), f2bf(v[1]), f2bf(v[2]), f2bf(v[3])};
        *reinterpret_cast<ushort4*>((unsigned short*)out + (size_t)idx * 4) = o;
    } else {
        f32x4 o = {v[0], v[1], v[2], v[3]};
        *reinterpret_cast<f32x4*>((float*)out + (size_t)idx * 4) = o;
    }
}

extern "C" void kernel_launch(void* const* d_in, const int* in_sizes, int n_in,
                              void* d_out, int out_size, void* d_ws, size_t ws_size,
                              hipStream_t stream) {
    const void* h    = d_in[0];
    const void* e0   = d_in[1];
    const void* e1   = d_in[2];
    const void* e2   = d_in[3];
    const void* W    = d_in[4];
    const void* as   = d_in[5];
    const void* ad   = d_in[6];
    const void* bias = d_in[7];
    const void* w1   = d_in[8];
    const void* b1   = d_in[9];
    const void* w2   = d_in[10];

    const int N = in_sizes[0] / 256;   // 50000
    const int E = in_sizes[1] / 2;     // 400000
    const int M = 3 * N;               // 150000 segments

    char* ws = (char*)d_ws;
    unsigned short* xw    = (unsigned short*)(ws + XW_OFF);
    _Float16*       zb    = (_Float16*)(ws + ZB_OFF);
    int*            csr   = (int*)(ws + CSR_OFF);
    int*            rs    = (int*)(ws + RS_OFF);
    int*            cur   = (int*)(ws + CUR_OFF);
    int*            bs    = (int*)(ws + BS_OFF);
    float*          as_   = (float*)(ws + AS_OFF);
    float*          ad_   = (float*)(ws + AD_OFF);
    unsigned short* Wt    = (unsigned short*)(ws + WT_OFF);
    _Float16*       w1t   = (_Float16*)(ws + W1T_OFF);
    float*          asf   = (float*)(ws + ASF_OFF);
    float*          adf   = (float*)(ws + ADF_OFF);
    float*          biasf = (float*)(ws + BIASF_OFF);
    float*          b1f   = (float*)(ws + B1F_OFF);
    float*          w2f   = (float*)(ws + W2F_OFF);
    float*          wsum  = (float*)(ws + WSUM_OFF);
    float*          beta  = (float*)(ws + BETA_OFF);
    int*            flags = (int*)(ws + FLAG_OFF);

    probe<<<1, 64, 0, stream>>>((const unsigned short*)h, (const unsigned int*)e0, flags);
    ingest_params<<<907, 256, 0, stream>>>(W, as, ad, bias, w1, b1, w2,
                                           Wt, w1t, asf, adf, biasf, b1f, w2f, flags);

    // CSR build (all 3 paths)
    int nb = (M + 1023) / 1024;                    // 147
    int eB = (3 * E + 255) / 256;                  // 4688
    hipMemsetAsync(cur, 0, M * sizeof(int), stream);
    hist<<<eB, 256, 0, stream>>>(e0, e1, e2, cur, E, N, flags);
    scan1<<<nb, 1024, 0, stream>>>(cur, rs, bs, M);
    scan2<<<1, 256, 0, stream>>>(bs, rs, nb, M);
    scan3<<<nb, 1024, 0, stream>>>(rs, bs, M);
    hipMemsetAsync(cur, 0, M * sizeof(int), stream);
    scatter<<<eB, 256, 0, stream>>>(e0, e1, e2, rs, cur, csr, E, N, flags);

    hipMemsetAsync(wsum, 0, 16, stream);

    int gemmBlocks = ((N / 16) * 2 + 3) / 4;       // 1563
    int aggBlocks  = (N + 3) / 4;                  // 12500
    for (int p = 0; p < 3; ++p) {
        gemm_xw_mfma<<<gemmBlocks, 256, 0, stream>>>(h, Wt + p * 65536, xw,
                                                     asf + p * 256, adf + p * 256,
                                                     as_, ad_, flags, N);
        agg_csr<<<aggBlocks, 256, 0, stream>>>(csr, rs, as_, ad_, xw, biasf, zb, N, p);
    }

    int semBlocks = (M / 16 + 3) / 4;              // 2344
    sem_w_mfma<<<semBlocks, 256, 0, stream>>>(zb, w1t, b1f, w2f, wsum, M);
    beta_kernel<<<1, 64, 0, stream>>>(wsum, beta, 1.0f / (float)N);
    combine<<<(N * 64 + 255) / 256, 256, 0, stream>>>(zb, beta, d_out, flags);
}

// Round 6
// 667.563 us; speedup vs baseline: 5.9860x; 1.1127x over previous
//
#include <hip/hip_runtime.h>
#include <hip/hip_bf16.h>

// ---------- helpers ----------
__device__ __forceinline__ float bf2f(unsigned short u) {
    union { unsigned int i; float f; } x;
    x.i = ((unsigned int)u) << 16;
    return x.f;
}
__device__ __forceinline__ unsigned short f2bf(float f) {
    union { float f; unsigned int u; } x; x.f = f;
    unsigned int r = x.u + 0x7FFFu + ((x.u >> 16) & 1u);
    return (unsigned short)(r >> 16);
}
__device__ __forceinline__ float fast_tanh(float x) {
    float a = fabsf(x);
    float t = __expf(2.f * a);
    float r = 1.f - 2.f / (t + 1.f);
    return copysignf(r, x);
}

typedef __bf16    bf16x8 __attribute__((ext_vector_type(8)));
typedef _Float16  f16x8  __attribute__((ext_vector_type(8)));
typedef _Float16  f16x4  __attribute__((ext_vector_type(4)));
typedef float     f32x4  __attribute__((ext_vector_type(4)));

// ---------- workspace byte offsets (total ~110.5 MB) ----------
#define XW_OFF     0UL            // N*256 bf16      = 25,600,000
#define ZB_OFF     25600000UL     // 3N*256 f16      = 76,800,000 (bias folded)
#define CSR_OFF    102400000UL    // 3E int32        =  4,800,000
#define RS_OFF     107200000UL    // (3N+1) int32
#define CUR_OFF    107800064UL    // 3N int32
#define BS_OFF     108400128UL    // 256 int32
#define AS_OFF     108401152UL    // N*4 f32
#define AD_OFF     109201152UL    // N*4 f32
#define WT_OFF     110001152UL    // 3*256*256 bf16 (transposed W)
#define W1T_OFF    110394368UL    // 128*256 f16 (transposed w1)
#define ASF_OFF    110459904UL    // 768 f32
#define ADF_OFF    110462976UL
#define BIASF_OFF  110466048UL
#define B1F_OFF    110469120UL
#define W2F_OFF    110469632UL
#define WSUM_OFF   110470144UL
#define BETA_OFF   110470208UL
#define FLAG_OFF   110470272UL

// ---------- P0: dtype probe ----------
__global__ void probe(const unsigned short* __restrict__ hraw,
                      const unsigned int* __restrict__ eraw,
                      int* __restrict__ flags) {
    if (threadIdx.x == 0 && blockIdx.x == 0) {
        int sane = 0;
        for (int i = 0; i < 256; ++i) {
            unsigned int e = (hraw[i] >> 7) & 0xFF;
            if (hraw[i] != 0 && e >= 100 && e <= 150) sane++;
        }
        flags[0] = (sane >= 220) ? 1 : 0;   // 1 = bf16 inputs/outputs
        int zeros = 0;
        for (int i = 1; i < 256; i += 2) if (eraw[i] == 0u) zeros++;
        flags[1] = (zeros >= 120) ? 1 : 0;  // 1 = int64 indices
    }
}

__device__ __forceinline__ float rd_f(const void* p, int j, bool bf) {
    return bf ? bf2f(((const unsigned short*)p)[j]) : ((const float*)p)[j];
}
__device__ __forceinline__ int rd_i(const void* p, long long j, bool i64) {
    return i64 ? (int)((const long long*)p)[j] : ((const int*)p)[j];
}

// ---------- P1: canonicalize params ----------
__global__ void ingest_params(const void* W, const void* as, const void* ad, const void* bias,
                              const void* w1, const void* b1, const void* w2,
                              unsigned short* Wt, _Float16* w1t,
                              float* asf, float* adf, float* biasf,
                              float* b1f, float* w2f,
                              const int* __restrict__ flags) {
    int i = blockIdx.x * 256 + threadIdx.x;
    bool bf = flags[0] != 0;
    if (i < 196608) {                              // Wt[p][n][k] = W[p][k][n]
        int p = i >> 16, n = (i >> 8) & 255, k = i & 255;
        Wt[i] = f2bf(rd_f(W, p * 65536 + k * 256 + n, bf));
    } else if (i < 229376) {                       // w1t[n][k] = w1[k][n], fp16
        int j = i - 196608;
        int n = j >> 8, k = j & 255;
        w1t[j] = (_Float16)rd_f(w1, k * 128 + n, bf);
    } else if (i < 230144) {
        int j = i - 229376; asf[j] = rd_f(as, j, bf);
    } else if (i < 230912) {
        int j = i - 230144; adf[j] = rd_f(ad, j, bf);
    } else if (i < 231680) {
        int j = i - 230912; biasf[j] = rd_f(bias, j, bf);
    } else if (i < 231808) {
        int j = i - 231680; b1f[j] = rd_f(b1, j, bf);
    } else if (i < 231936) {
        int j = i - 231808; w2f[j] = rd_f(w2, j, bf);
    }
}

// ---------- CSR build ----------
__global__ void hist(const void* e0, const void* e1, const void* e2,
                     int* __restrict__ cnt, int E, int N, const int* __restrict__ flags) {
    int i = blockIdx.x * 256 + threadIdx.x;
    if (i >= 3 * E) return;
    int p = i / E, e = i - p * E;
    const void* ep = (p == 0) ? e0 : (p == 1) ? e1 : e2;
    int dst = rd_i(ep, (long long)E + e, flags[1] != 0);
    atomicAdd(&cnt[p * N + dst], 1);
}

__global__ void scan1(const int* __restrict__ cnt, int* __restrict__ rs,
                      int* __restrict__ bs, int M) {
    __shared__ int s[1024];
    int t = threadIdx.x, i = blockIdx.x * 1024 + t;
    int v = (i < M) ? cnt[i] : 0;
    s[t] = v; __syncthreads();
    for (int o = 1; o < 1024; o <<= 1) {
        int tmp = (t >= o) ? s[t - o] : 0;
        __syncthreads();
        s[t] += tmp;
        __syncthreads();
    }
    if (i < M) rs[i] = s[t] - v;
    if (t == 1023) bs[blockIdx.x] = s[t];
}

__global__ void scan2(int* __restrict__ bs, int* __restrict__ rs, int nb, int M) {
    __shared__ int s[256];
    int t = threadIdx.x;
    int v = (t < nb) ? bs[t] : 0;
    s[t] = v; __syncthreads();
    for (int o = 1; o < 256; o <<= 1) {
        int tmp = (t >= o) ? s[t - o] : 0;
        __syncthreads();
        s[t] += tmp;
        __syncthreads();
    }
    if (t < nb) bs[t] = s[t] - v;
    if (t == nb - 1) rs[M] = s[t];
}

__global__ void scan3(int* __restrict__ rs, const int* __restrict__ bs, int M) {
    int i = blockIdx.x * 1024 + threadIdx.x;
    if (i < M) rs[i] += bs[blockIdx.x];
}

__global__ void scatter(const void* e0, const void* e1, const void* e2,
                        const int* __restrict__ rs, int* __restrict__ cur,
                        int* __restrict__ csr, int E, int N,
                        const int* __restrict__ flags) {
    int i = blockIdx.x * 256 + threadIdx.x;
    if (i >= 3 * E) return;
    int p = i / E, e = i - p * E;
    const void* ep = (p == 0) ? e0 : (p == 1) ? e1 : e2;
    bool i64 = flags[1] != 0;
    int src = rd_i(ep, e, i64);
    int dst = rd_i(ep, (long long)E + e, i64);
    int seg = p * N + dst;
    int pos = rs[seg] + atomicAdd(&cur[seg], 1);
    csr[pos] = src;
}

// ---------- K1: xw = h @ W[p] (MFMA, B in swizzled LDS, wave = 64r x 128c) ----------
__global__ __launch_bounds__(256, 2)
void gemm_xw_mfma(const void* __restrict__ h,
                  const unsigned short* __restrict__ Wtp,   // [256 n][256 k] bf16
                  unsigned short* __restrict__ xw,
                  const float* __restrict__ asf,            // [256] this path
                  const float* __restrict__ adf,
                  float* __restrict__ as_, float* __restrict__ ad_,
                  const int* __restrict__ flags, int N) {
    __shared__ __bf16 Bs[32768];        // 64 KB: 128 rows x 256 k, 16B-chunk XOR swizzle
    int tid  = threadIdx.x;
    int ch   = blockIdx.x & 1;          // col half
    int rg   = blockIdx.x >> 1;         // row group (256 rows)
    // stage B half into LDS (chunk c of row r -> slot c ^ (r&7))
    {
        const bf16x8* src = (const bf16x8*)Wtp;
#pragma unroll
        for (int it = 0; it < 16; ++it) {
            int c = it * 256 + tid;
            int row = c >> 5, cv = c & 31;
            *(bf16x8*)(Bs + ((row << 5) + (cv ^ (row & 7))) * 8) =
                src[(ch * 128 + row) * 32 + cv];
        }
    }
    __syncthreads();

    int wave = tid >> 6, lane = tid & 63;
    int l15 = lane & 15, quad = lane >> 4;
    int sw  = l15 & 7;
    int row0 = rg * 256 + wave * 64;
    bool bfm = flags[0] != 0;

    int lr[4];
#pragma unroll
    for (int rt = 0; rt < 4; ++rt) lr[rt] = min(row0 + rt * 16 + l15, N - 1);

    f32x4 acc[4][8];
#pragma unroll
    for (int rt = 0; rt < 4; ++rt)
#pragma unroll
        for (int tn = 0; tn < 8; ++tn) acc[rt][tn] = (f32x4){0.f, 0.f, 0.f, 0.f};

#pragma unroll
    for (int c0 = 0; c0 < 32; c0 += 4) {          // k chunk base (16B units), k = c0*8
        int kc = c0 * 8;
        bf16x8 a[4];
#pragma unroll
        for (int rt = 0; rt < 4; ++rt) {
            size_t off = (size_t)lr[rt] * 256 + kc + quad * 8;
            if (bfm) {
                a[rt] = *reinterpret_cast<const bf16x8*>((const __bf16*)h + off);
            } else {
                f32x4 u0 = *reinterpret_cast<const f32x4*>((const float*)h + off);
                f32x4 u1 = *reinterpret_cast<const f32x4*>((const float*)h + off + 4);
#pragma unroll
                for (int j = 0; j < 4; ++j) { a[rt][j] = (__bf16)u0[j]; a[rt][4 + j] = (__bf16)u1[j]; }
            }
        }
#pragma unroll
        for (int tn = 0; tn < 8; ++tn) {
            int row = tn * 16 + l15;
            bf16x8 b = *reinterpret_cast<const bf16x8*>(
                Bs + ((row << 5) + (((c0 + quad)) ^ sw)) * 8);
#pragma unroll
            for (int rt = 0; rt < 4; ++rt)
                acc[rt][tn] = __builtin_amdgcn_mfma_f32_16x16x32_bf16(a[rt], b, acc[rt][tn], 0, 0, 0);
        }
    }

    // epilogue: store xw + fused alpha (wave owns heads {2ch, 2ch+1})
#pragma unroll
    for (int rt = 0; rt < 4; ++rt) {
        int rbase = row0 + rt * 16 + quad * 4;
#pragma unroll
        for (int tn = 0; tn < 8; ++tn) {
            int c = ch * 128 + tn * 16 + l15;
#pragma unroll
            for (int i = 0; i < 4; ++i) {
                int r = rbase + i;
                if (r < N) xw[(size_t)r * 256 + c] = f2bf(acc[rt][tn][i]);
            }
        }
        float ss[2][4] = {{0.f,0.f,0.f,0.f},{0.f,0.f,0.f,0.f}};
        float dd[2][4] = {{0.f,0.f,0.f,0.f},{0.f,0.f,0.f,0.f}};
#pragma unroll
        for (int tn = 0; tn < 8; ++tn) {
            int c = ch * 128 + tn * 16 + l15;
            float sv = asf[c], dv = adf[c];
            int hs = tn >> 2;
#pragma unroll
            for (int i = 0; i < 4; ++i) {
                ss[hs][i] += acc[rt][tn][i] * sv;
                dd[hs][i] += acc[rt][tn][i] * dv;
            }
        }
#pragma unroll
        for (int hs = 0; hs < 2; ++hs)
#pragma unroll
            for (int i = 0; i < 4; ++i) {
                float s = ss[hs][i], d = dd[hs][i];
                s += __shfl_xor(s, 1); d += __shfl_xor(d, 1);
                s += __shfl_xor(s, 2); d += __shfl_xor(d, 2);
                s += __shfl_xor(s, 4); d += __shfl_xor(d, 4);
                s += __shfl_xor(s, 8); d += __shfl_xor(d, 8);
                ss[hs][i] = s; dd[hs][i] = d;
            }
        if (l15 == 0) {
#pragma unroll
            for (int hs = 0; hs < 2; ++hs)
#pragma unroll
                for (int i = 0; i < 4; ++i) {
                    int r = rbase + i;
                    if (r < N) {
                        int g = r * 4 + ch * 2 + hs;
                        as_[g] = ss[hs][i];
                        ad_[g] = dd[hs][i];
                    }
                }
        }
    }
}

__device__ __forceinline__ float leaky(float v) { return v > 0.f ? v : 0.2f * v; }

// ---------- K5: CSR online-softmax aggregate -> z' fp16 (bias folded) ----------
__global__ void agg_csr(const int* __restrict__ csr, const int* __restrict__ rs,
                        const float* __restrict__ as_, const float* __restrict__ ad_,
                        const unsigned short* __restrict__ xw,
                        const float* __restrict__ biasf,
                        _Float16* __restrict__ zb, int N, int p) {
    int d = blockIdx.x * 4 + (threadIdx.x >> 6);
    if (d >= N) return;
    int lane = threadIdx.x & 63;
    int h = lane >> 4;
    int seg = p * N + d;
    int start = rs[seg], end = rs[seg + 1];

    float adh = ad_[d * 4 + h];
    float m = leaky(as_[d * 4 + h] + adh);
    float l = 1.f;
    float a0, a1, a2, a3;
    {
        ushort4 u = *reinterpret_cast<const ushort4*>(xw + (size_t)d * 256 + lane * 4);
        a0 = bf2f(u.x); a1 = bf2f(u.y); a2 = bf2f(u.z); a3 = bf2f(u.w);
    }
    int srcA = (start < end) ? csr[start] : 0;
    for (int j = start; j < end; ++j) {
        int srcB = (j + 1 < end) ? csr[j + 1] : 0;
        float v = leaky(as_[srcA * 4 + h] + adh);
        ushort4 u = *reinterpret_cast<const ushort4*>(xw + (size_t)srcA * 256 + lane * 4);
        float mn = fmaxf(m, v);
        float c = __expf(m - mn);
        float w = __expf(v - mn);
        m = mn;
        l = l * c + w;
        a0 = a0 * c + w * bf2f(u.x);
        a1 = a1 * c + w * bf2f(u.y);
        a2 = a2 * c + w * bf2f(u.z);
        a3 = a3 * c + w * bf2f(u.w);
        srcA = srcB;
    }
    float inv = 1.f / l;
    int col = lane * 4;
    const float* bp = biasf + p * 256 + col;
    f16x4 o = {(_Float16)(a0 * inv + bp[0]), (_Float16)(a1 * inv + bp[1]),
               (_Float16)(a2 * inv + bp[2]), (_Float16)(a3 * inv + bp[3])};
    *reinterpret_cast<f16x4*>(zb + ((size_t)d * 3 + p) * 256 + col) = o;
}

// ---------- K6: semantic attention (f16 MFMA, w1 in swizzled LDS, wave = 64r) ----------
__global__ __launch_bounds__(256, 2)
void sem_w_mfma(const _Float16* __restrict__ zb,
                const _Float16* __restrict__ w1t,   // [128 n][256 k] f16
                const float* __restrict__ b1f,
                const float* __restrict__ w2f,
                float* __restrict__ wsum, int rows) {
    __shared__ _Float16 Bs[32768];      // 64 KB, 16B-chunk XOR swizzle
    int tid = threadIdx.x;
    {
        const f16x8* src = (const f16x8*)w1t;
#pragma unroll
        for (int it = 0; it < 16; ++it) {
            int c = it * 256 + tid;
            int row = c >> 5, cv = c & 31;
            *(f16x8*)(Bs + ((row << 5) + (cv ^ (row & 7))) * 8) = src[c];
        }
    }
    __syncthreads();

    int wave = tid >> 6, lane = tid & 63;
    int l15 = lane & 15, quad = lane >> 4;
    int sw  = l15 & 7;
    int row0 = blockIdx.x * 256 + wave * 64;

    int lr[4];
#pragma unroll
    for (int rt = 0; rt < 4; ++rt) lr[rt] = min(row0 + rt * 16 + l15, rows - 1);

    f32x4 acc[4][8];
#pragma unroll
    for (int rt = 0; rt < 4; ++rt)
#pragma unroll
        for (int tn = 0; tn < 8; ++tn) acc[rt][tn] = (f32x4){0.f, 0.f, 0.f, 0.f};

#pragma unroll
    for (int c0 = 0; c0 < 32; c0 += 4) {
        int kc = c0 * 8;
        f16x8 a[4];
#pragma unroll
        for (int rt = 0; rt < 4; ++rt)
            a[rt] = *reinterpret_cast<const f16x8*>(zb + (size_t)lr[rt] * 256 + kc + quad * 8);
#pragma unroll
        for (int tn = 0; tn < 8; ++tn) {
            int row = tn * 16 + l15;
            f16x8 b = *reinterpret_cast<const f16x8*>(
                Bs + ((row << 5) + ((c0 + quad) ^ sw)) * 8);
#pragma unroll
            for (int rt = 0; rt < 4; ++rt)
                acc[rt][tn] = __builtin_amdgcn_mfma_f32_16x16x32_f16(a[rt], b, acc[rt][tn], 0, 0, 0);
        }
    }

    // epilogue: per-lane 3-bin accumulation, then wave reduce + 3 global atomics
    float bins[3] = {0.f, 0.f, 0.f};
#pragma unroll
    for (int rt = 0; rt < 4; ++rt) {
        float rowsum[4] = {0.f, 0.f, 0.f, 0.f};
#pragma unroll
        for (int tn = 0; tn < 8; ++tn) {
            int col = tn * 16 + l15;
            float b1v = b1f[col], w2v = w2f[col];
#pragma unroll
            for (int i = 0; i < 4; ++i)
                rowsum[i] += fast_tanh(acc[rt][tn][i] + b1v) * w2v;
        }
#pragma unroll
        for (int i = 0; i < 4; ++i) {
            rowsum[i] += __shfl_xor(rowsum[i], 1);
            rowsum[i] += __shfl_xor(rowsum[i], 2);
            rowsum[i] += __shfl_xor(rowsum[i], 4);
            rowsum[i] += __shfl_xor(rowsum[i], 8);
        }
        if (l15 == 0) {
#pragma unroll
            for (int i = 0; i < 4; ++i) {
                int r = row0 + rt * 16 + quad * 4 + i;
                if (r < rows) bins[r % 3] += rowsum[i];
            }
        }
    }
#pragma unroll
    for (int b = 0; b < 3; ++b) {
        bins[b] += __shfl_xor(bins[b], 16);
        bins[b] += __shfl_xor(bins[b], 32);
    }
    if (lane == 0) {
#pragma unroll
        for (int b = 0; b < 3; ++b) atomicAdd(&wsum[b], bins[b]);
    }
}

// ---------- K7: beta = softmax(mean) ----------
__global__ void beta_kernel(const float* __restrict__ wsum, float* __restrict__ beta, float invN) {
    if (threadIdx.x == 0) {
        float w0 = wsum[0] * invN, w1 = wsum[1] * invN, w2 = wsum[2] * invN;
        float mx = fmaxf(w0, fmaxf(w1, w2));
        float e0 = __expf(w0 - mx), e1 = __expf(w1 - mx), e2 = __expf(w2 - mx);
        float s = e0 + e1 + e2;
        beta[0] = e0 / s; beta[1] = e1 / s; beta[2] = e2 / s;
    }
}

// ---------- K8: out = sum_p beta[p]*z'[:,p,:] ----------
__global__ void combine(const _Float16* __restrict__ zb,
                        const float* __restrict__ beta,
                        void* __restrict__ out, const int* __restrict__ flags) {
    int idx = blockIdx.x * 256 + threadIdx.x;    // over N*64
    int n = idx >> 6, c4 = (idx & 63) * 4;
    float b0 = beta[0], b1 = beta[1], b2 = beta[2];
    const _Float16* base = zb + (size_t)n * 768 + c4;
    f16x4 z0 = *reinterpret_cast<const f16x4*>(base);
    f16x4 z1 = *reinterpret_cast<const f16x4*>(base + 256);
    f16x4 z2 = *reinterpret_cast<const f16x4*>(base + 512);
    float v[4];
#pragma unroll
    for (int i = 0; i < 4; ++i)
        v[i] = b0 * (float)z0[i] + b1 * (float)z1[i] + b2 * (float)z2[i];
    if (flags[0]) {
        ushort4 o = {f2bf(v[0]), f2bf(v[1]), f2bf(v[2]), f2bf(v[3])};
        *reinterpret_cast<ushort4*>((unsigned short*)out + (size_t)idx * 4) = o;
    } else {
        f32x4 o = {v[0], v[1], v[2], v[3]};
        *reinterpret_cast<f32x4*>((float*)out + (size_t)idx * 4) = o;
    }
}

extern "C" void kernel_launch(void* const* d_in, const int* in_sizes, int n_in,
                              void* d_out, int out_size, void* d_ws, size_t ws_size,
                              hipStream_t stream) {
    const void* h    = d_in[0];
    const void* e0   = d_in[1];
    const void* e1   = d_in[2];
    const void* e2   = d_in[3];
    const void* W    = d_in[4];
    const void* as   = d_in[5];
    const void* ad   = d_in[6];
    const void* bias = d_in[7];
    const void* w1   = d_in[8];
    const void* b1   = d_in[9];
    const void* w2   = d_in[10];

    const int N = in_sizes[0] / 256;   // 50000
    const int E = in_sizes[1] / 2;     // 400000
    const int M = 3 * N;               // 150000 segments

    char* ws = (char*)d_ws;
    unsigned short* xw    = (unsigned short*)(ws + XW_OFF);
    _Float16*       zb    = (_Float16*)(ws + ZB_OFF);
    int*            csr   = (int*)(ws + CSR_OFF);
    int*            rs    = (int*)(ws + RS_OFF);
    int*            cur   = (int*)(ws + CUR_OFF);
    int*            bs    = (int*)(ws + BS_OFF);
    float*          as_   = (float*)(ws + AS_OFF);
    float*          ad_   = (float*)(ws + AD_OFF);
    unsigned short* Wt    = (unsigned short*)(ws + WT_OFF);
    _Float16*       w1t   = (_Float16*)(ws + W1T_OFF);
    float*          asf   = (float*)(ws + ASF_OFF);
    float*          adf   = (float*)(ws + ADF_OFF);
    float*          biasf = (float*)(ws + BIASF_OFF);
    float*          b1f   = (float*)(ws + B1F_OFF);
    float*          w2f   = (float*)(ws + W2F_OFF);
    float*          wsum  = (float*)(ws + WSUM_OFF);
    float*          beta  = (float*)(ws + BETA_OFF);
    int*            flags = (int*)(ws + FLAG_OFF);

    probe<<<1, 64, 0, stream>>>((const unsigned short*)h, (const unsigned int*)e0, flags);
    ingest_params<<<907, 256, 0, stream>>>(W, as, ad, bias, w1, b1, w2,
                                           Wt, w1t, asf, adf, biasf, b1f, w2f, flags);

    // CSR build (all 3 paths)
    int nb = (M + 1023) / 1024;                    // 147
    int eB = (3 * E + 255) / 256;                  // 4688
    hipMemsetAsync(cur, 0, M * sizeof(int), stream);
    hist<<<eB, 256, 0, stream>>>(e0, e1, e2, cur, E, N, flags);
    scan1<<<nb, 1024, 0, stream>>>(cur, rs, bs, M);
    scan2<<<1, 256, 0, stream>>>(bs, rs, nb, M);
    scan3<<<nb, 1024, 0, stream>>>(rs, bs, M);
    hipMemsetAsync(cur, 0, M * sizeof(int), stream);
    scatter<<<eB, 256, 0, stream>>>(e0, e1, e2, rs, cur, csr, E, N, flags);

    hipMemsetAsync(wsum, 0, 16, stream);

    int gemmBlocks = ((N + 255) / 256) * 2;        // 392
    int aggBlocks  = (N + 3) / 4;                  // 12500
    for (int p = 0; p < 3; ++p) {
        gemm_xw_mfma<<<gemmBlocks, 256, 0, stream>>>(h, Wt + p * 65536, xw,
                                                     asf + p * 256, adf + p * 256,
                                                     as_, ad_, flags, N);
        agg_csr<<<aggBlocks, 256, 0, stream>>>(csr, rs, as_, ad_, xw, biasf, zb, N, p);
    }

    int semBlocks = (M + 255) / 256;               // 586
    sem_w_mfma<<<semBlocks, 256, 0, stream>>>(zb, w1t, b1f, w2f, wsum, M);
    beta_kernel<<<1, 64, 0, stream>>>(wsum, beta, 1.0f / (float)N);
    combine<<<(N * 64 + 255) / 256, 256, 0, stream>>>(zb, beta, d_out, flags);
}